// Round 11
// baseline (6136.490 us; speedup 1.0000x reference)
//
#include <hip/hip_runtime.h>
#include <hip/hip_bf16.h>

#define SEQ 2048
#define DIM 1024
#define RNK 16
#define NL 4
#define KT 7
#define BATCH 2
#define HID 4096
#define VOC 32000
#define BNROWS (BATCH*SEQ)
#define CHK 128
#define NCH (SEQ/CHK)
#define PRMS 128
#define KAPP 160   // apply-GEMM K: 128 (intra) + 16 (inter) + 16 pad

typedef __hip_bfloat16 bf16;
typedef __attribute__((ext_vector_type(8))) short bh8;
typedef __attribute__((ext_vector_type(4))) float vf4;

__device__ __forceinline__ float bfu(unsigned int u) { u <<= 16; return __builtin_bit_cast(float, u); }
__device__ __forceinline__ unsigned short f2bu(float x) { bf16 t = __float2bfloat16(x); return __builtin_bit_cast(unsigned short, t); }
__device__ __forceinline__ float b2f(bf16 x) { return __bfloat162float(x); }
__device__ __forceinline__ float sigm(float x) { return 1.f / (1.f + expf(-x)); }
__device__ __forceinline__ float gelu_t(float x) {
    float u = 0.7978845608028654f * (x + 0.044715f * x * x * x);
    return 0.5f * x * (1.f + tanhf(u));
}

// async global->LDS, 16B per lane. LDS dest = wave-uniform base + lane*16.
__device__ __forceinline__ void gld16(const bf16* g, bf16* l) {
    __builtin_amdgcn_global_load_lds(
        (const __attribute__((address_space(1))) void*)g,
        (__attribute__((address_space(3))) void*)l,
        16, 0, 0);
}

// ---------------- embedding gather ----------------
__global__ void embed_kernel(const int* __restrict__ tokens, const float* __restrict__ emb,
                             float* __restrict__ h) {
    int row = blockIdx.x;
    int tok = tokens[row];
    const float4* src = (const float4*)(emb + (size_t)tok * DIM);
    float4* dst = (float4*)(h + (size_t)row * DIM);
    dst[threadIdx.x] = src[threadIdx.x];
}

// ---------------- rmsnorm -> bf16 ----------------
__global__ void rmsnorm_kernel(const float* __restrict__ in, const float* __restrict__ wt,
                               bf16* __restrict__ out) {
    int row = blockIdx.x;
    int tx = threadIdx.x;
    float4 v = ((const float4*)(in + (size_t)row * DIM))[tx];
    float ss = v.x * v.x + v.y * v.y + v.z * v.z + v.w * v.w;
#pragma unroll
    for (int off = 32; off > 0; off >>= 1) ss += __shfl_down(ss, off);
    __shared__ float red[4];
    int lane = tx & 63, wv = tx >> 6;
    if (lane == 0) red[wv] = ss;
    __syncthreads();
    float tot = red[0] + red[1] + red[2] + red[3];
    float scale = rsqrtf(tot * (1.f / DIM) + 1e-6f);
    float4 w4 = ((const float4*)wt)[tx];
    uint2 o;
    o.x = f2bu(v.x * scale * w4.x) | ((unsigned int)f2bu(v.y * scale * w4.y) << 16);
    o.y = f2bu(v.z * scale * w4.z) | ((unsigned int)f2bu(v.w * scale * w4.w) << 16);
    *(uint2*)(out + (size_t)row * DIM + tx * 4) = o;
}

// ---------------- weight transpose + cast: in (K x Nc) f32 -> out (Nc x K) bf16 ----------------
__global__ void transpose_cast_kernel(const float* __restrict__ in, bf16* __restrict__ out,
                                      int K, int Nc) {
    __shared__ float tile[32][33];
    int n0 = blockIdx.x * 32, k0 = blockIdx.y * 32;
    int tx = threadIdx.x & 31, ty = threadIdx.x >> 5;
#pragma unroll
    for (int i = 0; i < 32; i += 8)
        tile[ty + i][tx] = in[(size_t)(k0 + ty + i) * Nc + n0 + tx];
    __syncthreads();
#pragma unroll
    for (int i = 0; i < 32; i += 8)
        out[(size_t)(n0 + ty + i) * K + k0 + tx] = __float2bfloat16(tile[tx][ty + i]);
}

// ---------------- per-layer params ----------------
__global__ void prep_kernel(const float* __restrict__ dlog, const float* __restrict__ alog,
                            const float* __restrict__ glog, const float* __restrict__ kern,
                            float* __restrict__ prm) {
    int l = blockIdx.x, t = threadIdx.x;
    float* p = prm + l * PRMS;
    if (t < RNK) {
        float g = 0.85f + 0.15f * sigm(dlog[l * RNK + t]);
        float lg = logf(g);
        p[t] = g;
        p[16 + t] = lg;
        p[32 + t] = expf(lg * (float)CHK);
        p[48 + t] = sigm(alog[l * RNK + t]);   // ACAP = 1.0
    }
    if (t < KT) {
        float gate = sigm(glog[l]);
        p[64 + t] = gate * kern[l * KT + t];
    }
}

// ---------------- pack u,v (D x R each) -> uvT (32 x D) bf16 per layer ----------------
__global__ void prep_uv_kernel(const float* __restrict__ u, const float* __restrict__ v,
                               bf16* __restrict__ uvT) {
    int l = blockIdx.y;
    int k = blockIdx.x * 256 + threadIdx.x;
    const float* ul = u + (size_t)l * DIM * RNK;
    const float* vl = v + (size_t)l * DIM * RNK;
    bf16* o = uvT + (size_t)l * 32 * DIM;
#pragma unroll
    for (int r = 0; r < RNK; ++r) {
        o[(size_t)r * DIM + k] = __float2bfloat16(ul[(size_t)k * RNK + r]);
        o[(size_t)(RNK + r) * DIM + k] = __float2bfloat16(vl[(size_t)k * RNK + r]);
    }
}

// ---------------- gated causal conv: Z = gate * conv(hn) ----------------
__global__ void conv_kernel(const bf16* __restrict__ hn, const float* __restrict__ prm,
                            float* __restrict__ Z) {
    int t = blockIdx.x * 256 + threadIdx.x;
    int d4 = (t & 255) * 4;
    int row = t >> 8;
    int n = row & (SEQ - 1);
    float a0 = 0, a1 = 0, a2 = 0, a3 = 0;
#pragma unroll
    for (int kk = 0; kk < KT; ++kk) {
        if (n - kk < 0) break;
        float wv = prm[64 + kk];
        uint2 hv = *(const uint2*)(hn + (size_t)(row - kk) * DIM + d4);
        a0 += wv * bfu(hv.x & 0xffffu);
        a1 += wv * bfu(hv.x >> 16);
        a2 += wv * bfu(hv.y & 0xffffu);
        a3 += wv * bfu(hv.y >> 16);
    }
    float4 o = {a0, a1, a2, a3};
    *(float4*)(Z + (size_t)row * DIM + d4) = o;
}

// ---------------- q/k projection + l2norm via MFMA (16 rows / 1-wave block) ----------------
__global__ __launch_bounds__(64)
void qk_mfma_kernel(const bf16* __restrict__ hn, const bf16* __restrict__ uvT,
                    const float* __restrict__ prm, float* __restrict__ qa,
                    float* __restrict__ kn) {
    int row0 = blockIdx.x * 16;
    int lane = threadIdx.x;
    int fr = lane & 15, kf = (lane >> 4) * 8;
    vf4 accq = {}, acck = {};
#pragma unroll 4
    for (int kt = 0; kt < DIM / 32; ++kt) {
        int k0 = kt * 32;
        bh8 b0 = *(const bh8*)(uvT + (size_t)fr * DIM + k0 + kf);
        bh8 b1 = *(const bh8*)(uvT + (size_t)(16 + fr) * DIM + k0 + kf);
        bh8 a0 = *(const bh8*)(hn + (size_t)(row0 + fr) * DIM + k0 + kf);
        accq = __builtin_amdgcn_mfma_f32_16x16x32_bf16(a0, b0, accq, 0, 0, 0);
        acck = __builtin_amdgcn_mfma_f32_16x16x32_bf16(a0, b1, acck, 0, 0, 0);
    }
    int fq = lane >> 4;
    float alpha = prm[48 + fr];
#pragma unroll
    for (int j = 0; j < 4; ++j) {
        float qv = accq[j], kv = acck[j];
        float sq = qv * qv, sk = kv * kv;
#pragma unroll
        for (int mask = 1; mask < 16; mask <<= 1) {
            sq += __shfl_xor(sq, mask);
            sk += __shfl_xor(sk, mask);
        }
        int row = row0 + fq * 4 + j;
        qa[(size_t)row * RNK + fr] = qv / fmaxf(sqrtf(sq), 1e-8f) * alpha;
        kn[(size_t)row * RNK + fr] = kv / fmaxf(sqrtf(sk), 1e-8f);
    }
}

// ---------------- per-chunk transpose of hn into HB[bc][d][0..128) ----------------
__global__ void trans_hn_kernel(const bf16* __restrict__ hn, bf16* __restrict__ HB) {
    __shared__ bf16 tile[32][40];
    int bc = blockIdx.x;
    int d0 = blockIdx.y * 32, j0 = blockIdx.z * 32;
    int tx = threadIdx.x & 31, ty = threadIdx.x >> 5;
    size_t rowb = (size_t)bc * CHK;
#pragma unroll
    for (int i = 0; i < 32; i += 8)
        tile[ty + i][tx] = hn[(rowb + j0 + ty + i) * DIM + d0 + tx];
    __syncthreads();
    bf16* Hp = HB + (size_t)bc * DIM * KAPP;
#pragma unroll
    for (int i = 0; i < 32; i += 8)
        Hp[(size_t)(d0 + ty + i) * KAPP + j0 + tx] = tile[tx][ty + i];
}

// ---------------- scores + apply-A assembly + kdt (split over i-tiles) ----------------
__global__ void scores_kernel(const float* __restrict__ qa, const float* __restrict__ kn,
                              const float* __restrict__ prm, bf16* __restrict__ SA,
                              bf16* __restrict__ kdtB) {
    int bc = blockIdx.x;
    int yt = blockIdx.y;
    __shared__ float ptab[CHK][16];
    for (int e = threadIdx.x; e < CHK * 16; e += 256) {
        int tt = e >> 4, r = e & 15;
        ptab[tt][r] = expf(prm[16 + r] * (float)tt);
    }
    __syncthreads();
    size_t rowb = (size_t)bc * CHK;
    bf16* SAp = SA + (size_t)bc * CHK * KAPP;
    for (int e = threadIdx.x; e < 16 * CHK; e += 256) {
        int i = yt * 16 + (e >> 7), j = e & (CHK - 1);
        float vsum = 0.f;
        if (i >= j) {
            const float* qp = qa + (rowb + i) * RNK;
            const float* kp = kn + (rowb + j) * RNK;
#pragma unroll
            for (int r = 0; r < 16; ++r) vsum += qp[r] * ptab[i - j][r] * kp[r];
        }
        SAp[(size_t)i * KAPP + j] = __float2bfloat16(vsum);
    }
    for (int e = threadIdx.x; e < 16 * 32; e += 256) {
        int i = yt * 16 + (e >> 5), rr = e & 31;
        float w = 0.f;
        if (rr < 16) w = qa[(rowb + i) * RNK + rr] * expf(prm[16 + rr] * (float)(i + 1));
        SAp[(size_t)i * KAPP + CHK + rr] = __float2bfloat16(w);
    }
    bf16* kp2 = kdtB + (size_t)bc * RNK * CHK;
    for (int e = threadIdx.x; e < 2 * CHK; e += 256) {
        int r = 2 * yt + (e >> 7), j = e & (CHK - 1);
        kp2[(size_t)r * CHK + j] =
            __float2bfloat16(ptab[CHK - 1 - j][r] * kn[(rowb + j) * RNK + r]);
    }
}

// ---------------- chunkU via MFMA ----------------
__global__ __launch_bounds__(64)
void chunkU_kernel(const bf16* __restrict__ HB, const bf16* __restrict__ kdtB,
                   float* __restrict__ U) {
    int bc = blockIdx.x;
    int d0 = blockIdx.y * 64;
    int lane = threadIdx.x;
    int fr = lane & 15, kf = (lane >> 4) * 8;
    const bf16* Hp = HB + (size_t)bc * DIM * KAPP;
    const bf16* Kp = kdtB + (size_t)bc * RNK * CHK;
    vf4 acc[4] = {};
#pragma unroll
    for (int kt = 0; kt < 4; ++kt) {
        int k0 = kt * 32;
        bh8 bb = *(const bh8*)(Kp + (size_t)fr * CHK + k0 + kf);
#pragma unroll
        for (int m = 0; m < 4; ++m) {
            bh8 a = *(const bh8*)(Hp + (size_t)(d0 + m * 16 + fr) * KAPP + k0 + kf);
            acc[m] = __builtin_amdgcn_mfma_f32_16x16x32_bf16(a, bb, acc[m], 0, 0, 0);
        }
    }
    int fq = lane >> 4;
    float* Up = U + (size_t)bc * DIM * RNK;
#pragma unroll
    for (int m = 0; m < 4; ++m)
#pragma unroll
        for (int j = 0; j < 4; ++j)
            Up[(size_t)(d0 + m * 16 + fq * 4 + j) * RNK + fr] = acc[m][j];
}

// ---------------- chunk scan: P^T bf16 into HB[bc][d][128..144), 4 ranks/thread ----------------
__global__ void scanP_kernel(const float* __restrict__ U, const float* __restrict__ prm,
                             bf16* __restrict__ HB) {
    int g = blockIdx.x * 256 + threadIdx.x;
    int rq = g & 3;
    int d = (g >> 2) & (DIM - 1);
    int b = g >> 12;
    float gC[4], p[4];
#pragma unroll
    for (int q = 0; q < 4; ++q) { gC[q] = prm[32 + rq * 4 + q]; p[q] = 0.f; }
    for (int c = 0; c < NCH; ++c) {
        int bc = b * NCH + c;
        uint2 pk;
        pk.x = (unsigned int)f2bu(p[0]) | ((unsigned int)f2bu(p[1]) << 16);
        pk.y = (unsigned int)f2bu(p[2]) | ((unsigned int)f2bu(p[3]) << 16);
        *(uint2*)(HB + (size_t)bc * DIM * KAPP + (size_t)d * KAPP + CHK + rq * 4) = pk;
        float4 u4 = *(const float4*)(U + ((size_t)bc * DIM + d) * RNK + rq * 4);
        p[0] = gC[0] * p[0] + u4.x;
        p[1] = gC[1] * p[1] + u4.y;
        p[2] = gC[2] * p[2] + u4.z;
        p[3] = gC[3] * p[3] + u4.w;
    }
}

// ---------------- apply GEMM: Zb = bf16( Z + SA[bc] @ HB[bc]^T ) ----------------
__global__ __launch_bounds__(256)
void apply_gemm_kernel(const bf16* __restrict__ SA, const bf16* __restrict__ HB,
                       const float* __restrict__ Z, bf16* __restrict__ Zb) {
    __shared__ alignas(16) bf16 As[128][40];
    __shared__ alignas(16) bf16 Bs[128][40];
    int bc = blockIdx.y;
    int colB0 = blockIdx.x * 128;
    int t = threadIdx.x;
    int lane = t & 63, wid = t >> 6;
    int wr = wid >> 1, wc = wid & 1;
    vf4 acc[4][4] = {};
    const bf16* A = SA + (size_t)bc * CHK * KAPP;
    const bf16* BT = HB + (size_t)bc * DIM * KAPP;
    int r1 = t >> 2, ko1 = (t & 3) * 8;
    int fr = lane & 15, kf = (lane >> 4) * 8;
#pragma unroll
    for (int kt = 0; kt < 5; ++kt) {
        int k0 = kt * 32;
        int4 va1 = *(const int4*)(A + (size_t)r1 * KAPP + k0 + ko1);
        int4 va2 = *(const int4*)(A + (size_t)(r1 + 64) * KAPP + k0 + ko1);
        int4 vb1 = *(const int4*)(BT + (size_t)(colB0 + r1) * KAPP + k0 + ko1);
        int4 vb2 = *(const int4*)(BT + (size_t)(colB0 + r1 + 64) * KAPP + k0 + ko1);
        __syncthreads();
        *(int4*)&As[r1][ko1] = va1;
        *(int4*)&As[r1 + 64][ko1] = va2;
        *(int4*)&Bs[r1][ko1] = vb1;
        *(int4*)&Bs[r1 + 64][ko1] = vb2;
        __syncthreads();
        bh8 a[4], bb[4];
#pragma unroll
        for (int m = 0; m < 4; ++m) a[m] = *(const bh8*)&As[wr * 64 + m * 16 + fr][kf];
#pragma unroll
        for (int n = 0; n < 4; ++n) bb[n] = *(const bh8*)&Bs[wc * 64 + n * 16 + fr][kf];
#pragma unroll
        for (int m = 0; m < 4; ++m)
#pragma unroll
            for (int n = 0; n < 4; ++n)
                acc[m][n] = __builtin_amdgcn_mfma_f32_16x16x32_bf16(a[m], bb[n], acc[m][n], 0, 0, 0);
    }
    int fq = lane >> 4;
    size_t rowb = (size_t)bc * CHK;
#pragma unroll
    for (int m = 0; m < 4; ++m) {
#pragma unroll
        for (int n = 0; n < 4; ++n) {
            int col = colB0 + wc * 64 + n * 16 + fr;
#pragma unroll
            for (int j = 0; j < 4; ++j) {
                size_t row = rowb + wr * 64 + m * 16 + fq * 4 + j;
                size_t idx = row * DIM + col;
                Zb[idx] = __float2bfloat16(Z[idx] + acc[m][n][j]);
            }
        }
    }
}

// ---------------- 128-tile m97-structure GEMM (lda-parameterized) ----------------
// EPI 1: out = res + acc + bias (f32, in-place)
template <int EPI>
__global__ __launch_bounds__(256)
void gemm_kernel(const bf16* __restrict__ A, const bf16* __restrict__ BT,
                 const float* __restrict__ bias, const float* __restrict__ res,
                 float* __restrict__ outF, bf16* __restrict__ outB,
                 int M, int Nc, int K, int lda) {
    __shared__ alignas(16) bf16 As[128][32];
    __shared__ alignas(16) bf16 Bs[128][32];
    int gx = gridDim.x;
    int orig = blockIdx.y * gx + blockIdx.x;
    int qch = (gx * gridDim.y) >> 3;
    int wg = (orig & 7) * qch + (orig >> 3);
    int bn = wg % gx, bm = wg / gx;
    int t = threadIdx.x;
    int lane = t & 63, wid = t >> 6;
    int wr = wid >> 1, wc = wid & 1;
    vf4 acc[4][4] = {};
    const int rowA0 = bm * 128, colB0 = bn * 128;
    int fr = lane & 15, kf = (lane >> 4) * 8;
    int c0 = wid * 2;
    int lrow = lane >> 2;
    int lcol = (lane & 3) * 8;
    const bf16* Ag0 = A + (size_t)(rowA0 + c0 * 16 + lrow) * lda + lcol;
    const bf16* Ag1 = A + (size_t)(rowA0 + c0 * 16 + 16 + lrow) * lda + lcol;
    const bf16* Bg0 = BT + (size_t)(colB0 + c0 * 16 + lrow) * lda + lcol;
    const bf16* Bg1 = BT + (size_t)(colB0 + c0 * 16 + 16 + lrow) * lda + lcol;
    bf16* Al0 = &As[0][0] + c0 * 512;
    bf16* Al1 = Al0 + 512;
    bf16* Bl0 = &Bs[0][0] + c0 * 512;
    bf16* Bl1 = Bl0 + 512;
    int nk = K >> 5;
    for (int kt = 0; kt < nk; ++kt) {
        int k0 = kt * 32;
        __syncthreads();
        gld16(Ag0 + k0, Al0);
        gld16(Ag1 + k0, Al1);
        gld16(Bg0 + k0, Bl0);
        gld16(Bg1 + k0, Bl1);
        asm volatile("s_waitcnt vmcnt(0)" ::: "memory");
        __syncthreads();
        bh8 a[4], bb[4];
#pragma unroll
        for (int m = 0; m < 4; ++m) a[m] = *(const bh8*)&As[wr * 64 + m * 16 + fr][kf];
#pragma unroll
        for (int n = 0; n < 4; ++n) bb[n] = *(const bh8*)&Bs[wc * 64 + n * 16 + fr][kf];
#pragma unroll
        for (int m = 0; m < 4; ++m)
#pragma unroll
            for (int n = 0; n < 4; ++n)
                acc[m][n] = __builtin_amdgcn_mfma_f32_16x16x32_bf16(a[m], bb[n], acc[m][n], 0, 0, 0);
    }
    int fq = lane >> 4;
#pragma unroll
    for (int m = 0; m < 4; ++m) {
#pragma unroll
        for (int n = 0; n < 4; ++n) {
            int col = colB0 + wc * 64 + n * 16 + fr;
            float bv = bias[col];
#pragma unroll
            for (int j = 0; j < 4; ++j) {
                int row = rowA0 + wr * 64 + m * 16 + fq * 4 + j;
                size_t idx = (size_t)row * Nc + col;
                float v2 = acc[m][n][j] + bv;
                if (EPI == 1) v2 += res[idx];
                outF[idx] = v2;
            }
        }
    }
}

// ---------------- 256-tile 2-phase GEMM, BK=32, 64 KiB LDS -> 2 blocks/CU ----------------
// A[2][256][32] + B[2][256][32] bf16 = 64 KiB. Per K-tile(32):
// P0 {stage B(nd) 2 loads; vmcnt(2) [retires buf d's 4]; barrier; read B + A m0-3; 16 MFMA}
// P1 {stage A(nd) 2 loads; barrier; read A m4-7; 16 MFMA}
// Safety: B(nd) last read t-1 P0 -> t-1 P1 barrier -> t P0 stage;
//         A(nd) last read t-1 P1 -> t P0 barrier -> t P1 stage.
// Ledger: prologue [B0 x2, A0 x2]; P0 stage -> 6 outstanding -> vmcnt(2); last iter vmcnt(0).
// EPI 0: f32 out+bias; EPI 2: bf16 gelu(out+bias); EPI 4: bf16 split-K partial
#define SB __builtin_amdgcn_sched_barrier(0)
template <int EPI>
__global__ __launch_bounds__(512, 4)
void gemm256_kernel(const bf16* __restrict__ A, const bf16* __restrict__ BT,
                    const float* __restrict__ bias,
                    float* __restrict__ outF, bf16* __restrict__ outB,
                    int M, int Nc, int K, int lda) {
    extern __shared__ char smem[];
    bf16* Alds = (bf16*)smem;             // 2 x 8192 elems
    bf16* Blds = (bf16*)(smem + 32768);
    if (EPI == 4) {
        size_t zo = (size_t)blockIdx.z * K;
        A += zo; BT += zo;
        outB += (size_t)blockIdx.z * ((size_t)M * Nc);
    }
    int gx = gridDim.x, gy = gridDim.y;
    int orig = blockIdx.y * gx + blockIdx.x;
    int qch = (gx * gy) >> 3;
    int wg = (orig & 7) * qch + (orig >> 3);
    int bm = wg % gy, bn = wg / gy;   // column-major: XCD chunk shares bn panels
    int rowA0 = bm * 256, colB0 = bn * 256;
    int tid = threadIdx.x;
    int lane = tid & 63, wid = tid >> 6;
    int wm = wid >> 2, wn = wid & 3;
    int fr = lane & 15;
    int kf8 = ((((lane >> 4) & 3) ^ ((fr >> 1) & 3)) * 8);
    int srow = wid * 16 + (lane >> 2);
    int scol = (((lane & 3) ^ ((lane >> 3) & 3)) * 8);
    const bf16* Ags = A + (size_t)(rowA0 + srow) * lda + scol;
    const bf16* Bgs = BT + (size_t)(colB0 + srow) * lda + scol;
    int sbase = wid * 512;
    auto stA = [&](int d, int k0) {
        bf16* dst = Alds + d * 8192 + sbase;
        const bf16* src = Ags + k0;
        gld16(src, dst);
        gld16(src + (size_t)128 * lda, dst + 4096);
    };
    auto stB = [&](int d, int k0) {
        bf16* dst = Blds + d * 8192 + sbase;
        const bf16* src = Bgs + k0;
        gld16(src, dst);
        gld16(src + (size_t)128 * lda, dst + 4096);
    };
    const bf16* Ard = Alds + (size_t)(wm * 128 + fr) * 32 + kf8;
    const bf16* Brd = Blds + (size_t)(wn * 64 + fr) * 32 + kf8;
    vf4 acc[8][4] = {};
    int ntk = K >> 5;
    // prologue: tile 0 -> dbuf 0, queue [B0 x2, A0 x2]
    stB(0, 0); stA(0, 0);
    for (int t = 0; t < ntk; ++t) {
        int d = t & 1, nd = d ^ 1;
        int k1 = (t + 1) << 5;
        bool pf = (t + 1 < ntk);
        int dof = d * 8192;
        bh8 bF[4];
        // ---- P0: stage B(nd); vmcnt; barrier; read B + A m0-3; 16 MFMA acc[0..3] ----
        if (pf) { stB(nd, k1); asm volatile("s_waitcnt vmcnt(2)" ::: "memory"); }
        else    {              asm volatile("s_waitcnt vmcnt(0)" ::: "memory"); }
        SB; __builtin_amdgcn_s_barrier(); SB;
        {
            bh8 a0 = *(const bh8*)(Ard + dof + 0 * 512);
            bh8 a1 = *(const bh8*)(Ard + dof + 1 * 512);
            bh8 a2 = *(const bh8*)(Ard + dof + 2 * 512);
            bh8 a3 = *(const bh8*)(Ard + dof + 3 * 512);
#pragma unroll
            for (int n = 0; n < 4; ++n) bF[n] = *(const bh8*)(Brd + dof + n * 512);
            __builtin_amdgcn_s_setprio(1);
#pragma unroll
            for (int n = 0; n < 4; ++n) {
                acc[0][n] = __builtin_amdgcn_mfma_f32_16x16x32_bf16(a0, bF[n], acc[0][n], 0, 0, 0);
                acc[1][n] = __builtin_amdgcn_mfma_f32_16x16x32_bf16(a1, bF[n], acc[1][n], 0, 0, 0);
                acc[2][n] = __builtin_amdgcn_mfma_f32_16x16x32_bf16(a2, bF[n], acc[2][n], 0, 0, 0);
                acc[3][n] = __builtin_amdgcn_mfma_f32_16x16x32_bf16(a3, bF[n], acc[3][n], 0, 0, 0);
            }
            __builtin_amdgcn_s_setprio(0);
        }
        SB;
        // ---- P1: stage A(nd); barrier; read A m4-7; 16 MFMA acc[4..7] ----
        if (pf) stA(nd, k1);
        SB; __builtin_amdgcn_s_barrier(); SB;
        {
            bh8 a0 = *(const bh8*)(Ard + dof + 4 * 512);
            bh8 a1 = *(const bh8*)(Ard + dof + 5 * 512);
            bh8 a2 = *(const bh8*)(Ard + dof + 6 * 512);
            bh8 a3 = *(const bh8*)(Ard + dof + 7 * 512);
            __builtin_amdgcn_s_setprio(1);
#pragma unroll
            for (int n = 0; n < 4; ++n) {
                acc[4][n] = __builtin_amdgcn_mfma_f32_16x16x32_bf16(a0, bF[n], acc[4][n], 0, 0, 0);
                acc[5][n] = __builtin_amdgcn_mfma_f32_16x16x32_bf16(a1, bF[n], acc[5][n], 0, 0, 0);
                acc[6][n] = __builtin_amdgcn_mfma_f32_16x16x32_bf16(a2, bF[n], acc[6][n], 0, 0, 0);
                acc[7][n] = __builtin_amdgcn_mfma_f32_16x16x32_bf16(a3, bF[n], acc[7][n], 0, 0, 0);
            }
            __builtin_amdgcn_s_setprio(0);
        }
        SB;
    }
    int fq = lane >> 4;
#pragma unroll
    for (int mi = 0; mi < 8; ++mi) {
#pragma unroll
        for (int ni = 0; ni < 4; ++ni) {
            int col = colB0 + wn * 64 + ni * 16 + fr;
            float bv = (EPI == 4) ? 0.f : bias[col];
#pragma unroll
            for (int j = 0; j < 4; ++j) {
                int row = rowA0 + wm * 128 + mi * 16 + fq * 4 + j;
                size_t idx = (size_t)row * Nc + col;
                float v2 = acc[mi][ni][j] + bv;
                if (EPI == 2) outB[idx] = __float2bfloat16(gelu_t(v2));
                else if (EPI == 4) outB[idx] = __float2bfloat16(v2);
                else outF[idx] = v2;
            }
        }
    }
}

// ---------------- fused split-K combine (bf16 partials) + rmsnorm ----------------
__global__ void combine4_norm_kernel(const bf16* __restrict__ P, const float* __restrict__ bias,
                                     const float* __restrict__ nw, float* __restrict__ h,
                                     bf16* __restrict__ hnb) {
    int row = blockIdx.x;
    int tx = threadIdx.x;
    const size_t S = (size_t)BNROWS * DIM;
    size_t base = (size_t)row * DIM + tx * 4;
    float4 hv = *(float4*)(h + base);
    float4 bv = ((const float4*)bias)[tx];
    float s0 = bv.x, s1 = bv.y, s2 = bv.z, s3 = bv.w;
#pragma unroll
    for (int q = 0; q < 4; ++q) {
        uint2 pk = *(const uint2*)(P + q * S + base);
        s0 += bfu(pk.x & 0xffffu);
        s1 += bfu(pk.x >> 16);
        s2 += bfu(pk.y & 0xffffu);
        s3 += bfu(pk.y >> 16);
    }
    hv.x += s0; hv.y += s1; hv.z += s2; hv.w += s3;
    *(float4*)(h + base) = hv;
    float ss = hv.x * hv.x + hv.y * hv.y + hv.z * hv.z + hv.w * hv.w;
#pragma unroll
    for (int off = 32; off > 0; off >>= 1) ss += __shfl_down(ss, off);
    __shared__ float red[4];
    int lane = tx & 63, wv = tx >> 6;
    if (lane == 0) red[wv] = ss;
    __syncthreads();
    float tot = red[0] + red[1] + red[2] + red[3];
    float scale = rsqrtf(tot * (1.f / DIM) + 1e-6f);
    float4 w4 = ((const float4*)nw)[tx];
    uint2 o;
    o.x = f2bu(hv.x * scale * w4.x) | ((unsigned int)f2bu(hv.y * scale * w4.y) << 16);
    o.y = f2bu(hv.z * scale * w4.z) | ((unsigned int)f2bu(hv.w * scale * w4.w) << 16);
    *(uint2*)(hnb + (size_t)row * DIM + tx * 4) = o;
}

// ===================================================================
extern "C" void kernel_launch(void* const* d_in, const int* in_sizes, int n_in,
                              void* d_out, int out_size, void* d_ws, size_t ws_size,
                              hipStream_t stream) {
    (void)in_sizes; (void)n_in; (void)out_size; (void)ws_size;
    const int* tokens = (const int*)d_in[0];
    const float* emb = (const float*)d_in[1];
    const float* k1a_nw = (const float*)d_in[2];
    const float* k1a_w1 = (const float*)d_in[3];
    const float* k1a_b1 = (const float*)d_in[4];
    const float* k1a_w2 = (const float*)d_in[5];
    const float* k1a_b2 = (const float*)d_in[6];
    const float* k2_u = (const float*)d_in[7];
    const float* k2_v = (const float*)d_in[8];
    const float* k2_dlog = (const float*)d_in[9];
    const float* k2_alog = (const float*)d_in[10];
    const float* k2_glog = (const float*)d_in[11];
    const float* k2_kern = (const float*)d_in[12];
    const float* k2_pw = (const float*)d_in[13];
    const float* k2_pb = (const float*)d_in[14];
    const float* k2_n1w = (const float*)d_in[15];
    const float* k2_n2w = (const float*)d_in[16];
    const float* k2_w1 = (const float*)d_in[17];
    const float* k2_b1 = (const float*)d_in[18];
    const float* k2_w2 = (const float*)d_in[19];
    const float* k2_b2 = (const float*)d_in[20];
    const float* k1b_nw = (const float*)d_in[21];
    const float* k1b_w1 = (const float*)d_in[22];
    const float* k1b_b1 = (const float*)d_in[23];
    const float* k1b_w2 = (const float*)d_in[24];
    const float* k1b_b2 = (const float*)d_in[25];
    const float* k0_nw = (const float*)d_in[26];
    const float* head_w = (const float*)d_in[27];
    const float* head_b = (const float*)d_in[28];
    float* out = (float*)d_out;

    (void)hipFuncSetAttribute((const void*)gemm256_kernel<0>,
                              hipFuncAttributeMaxDynamicSharedMemorySize, 65536);
    (void)hipFuncSetAttribute((const void*)gemm256_kernel<2>,
                              hipFuncAttributeMaxDynamicSharedMemorySize, 65536);
    (void)hipFuncSetAttribute((const void*)gemm256_kernel<4>,
                              hipFuncAttributeMaxDynamicSharedMemorySize, 65536);

    // ---- workspace carve ----
    char* wsp = (char*)d_ws;
    auto alloc = [&](size_t bytes) -> char* {
        char* p = wsp;
        wsp += (bytes + 255) & ~(size_t)255;
        return p;
    };
    float* h   = (float*)alloc((size_t)BNROWS * DIM * 4);
    float* Z   = (float*)alloc((size_t)BNROWS * DIM * 4);
    bf16* hnb  = (bf16*)alloc((size_t)BNROWS * DIM * 2);
    bf16* Zb   = (bf16*)alloc((size_t)BNROWS * DIM * 2);
    bf16* t1b  = (bf16*)alloc((size_t)BNROWS * HID * 2);
    float* qaB = (float*)alloc((size_t)BNROWS * RNK * 4);
    float* knB = (float*)alloc((size_t)BNROWS * RNK * 4);
    float* U   = (float*)alloc((size_t)BATCH * NCH * DIM * RNK * 4);
    bf16* HB   = (bf16*)alloc((size_t)BATCH * NCH * DIM * KAPP * 2);
    bf16* SA   = (bf16*)alloc((size_t)BATCH * NCH * CHK * KAPP * 2);
    bf16* kdtB = (bf16*)alloc((size_t)BATCH * NCH * RNK * CHK * 2);
    float* prm = (float*)alloc((size_t)NL * PRMS * 4);
    bf16* uvT  = (bf16*)alloc((size_t)NL * 32 * DIM * 2);
    bf16* w1aT = (bf16*)alloc((size_t)HID * DIM * 2);
    bf16* w2aT = (bf16*)alloc((size_t)DIM * HID * 2);
    bf16* w1bT = (bf16*)alloc((size_t)HID * DIM * 2);
    bf16* w2bT = (bf16*)alloc((size_t)DIM * HID * 2);
    bf16* pwT  = (bf16*)alloc((size_t)NL * DIM * DIM * 2);
    bf16* w1T  = (bf16*)alloc((size_t)NL * DIM * HID * 2);
    bf16* w2T  = (bf16*)alloc((size_t)NL * HID * DIM * 2);
    bf16* headT = (bf16*)alloc((size_t)VOC * DIM * 2);
    bf16* Pk  = (bf16*)alloc((size_t)4 * BNROWS * DIM * 2);   // split-K partials (bf16)

    hipMemsetAsync(HB, 0, (size_t)BATCH * NCH * DIM * KAPP * 2, stream);

    auto T = [&](const float* in, bf16* o, int K, int Nc) {
        transpose_cast_kernel<<<dim3(Nc / 32, K / 32), 256, 0, stream>>>(in, o, K, Nc);
    };
    // ---- weight prep ----
    T(k1a_w1, w1aT, DIM, HID);
    T(k1a_w2, w2aT, HID, DIM);
    T(k1b_w1, w1bT, DIM, HID);
    T(k1b_w2, w2bT, HID, DIM);
    for (int l = 0; l < NL; ++l) {
        T(k2_pw + (size_t)l * DIM * DIM, pwT + (size_t)l * DIM * DIM, DIM, DIM);
        T(k2_w1 + (size_t)l * DIM * HID, w1T + (size_t)l * DIM * HID, DIM, HID);
        T(k2_w2 + (size_t)l * HID * DIM, w2T + (size_t)l * HID * DIM, HID, DIM);
    }
    T(head_w, headT, DIM, VOC);
    prep_kernel<<<NL, 32, 0, stream>>>(k2_dlog, k2_alog, k2_glog, k2_kern, prm);
    prep_uv_kernel<<<dim3(DIM / 256, NL), 256, 0, stream>>>(k2_u, k2_v, uvT);

    // mlp core: assumes hnb holds rmsnorm of h; leaves h updated and hnb = rmsnorm(h, nw_next)
    auto mlp_core = [&](const bf16* W1, const float* B1, const bf16* W2, const float* B2,
                        const float* nw_next) {
        gemm256_kernel<2><<<dim3(HID / 256, BNROWS / 256), 512, 65536, stream>>>(
            hnb, W1, B1, nullptr, t1b, BNROWS, HID, DIM, DIM);
        gemm256_kernel<4><<<dim3(DIM / 256, BNROWS / 256, 4), 512, 65536, stream>>>(
            t1b, W2, nullptr, nullptr, Pk, BNROWS, DIM, HID / 4, HID);
        combine4_norm_kernel<<<BNROWS, 256, 0, stream>>>(Pk, B2, nw_next, h, hnb);
    };

    // ---- forward ----
    embed_kernel<<<BNROWS, 256, 0, stream>>>(tokens, emb, h);
    rmsnorm_kernel<<<BNROWS, 256, 0, stream>>>(h, k1a_nw, hnb);
    mlp_core(w1aT, k1a_b1, w2aT, k1a_b2, k2_n1w);   // -> hnb = rmsnorm(h, n1w[0])

    for (int l = 0; l < NL; ++l) {
        const float* prm_l = prm + l * PRMS;
        conv_kernel<<<BNROWS, 256, 0, stream>>>(hnb, prm_l, Z);
        qk_mfma_kernel<<<BNROWS / 16, 64, 0, stream>>>(hnb, uvT + (size_t)l * 32 * DIM,
                                                       prm_l, qaB, knB);
        trans_hn_kernel<<<dim3(BATCH * NCH, DIM / 32, CHK / 32), 256, 0, stream>>>(hnb, HB);
        scores_kernel<<<dim3(BATCH * NCH, 8), 256, 0, stream>>>(qaB, knB, prm_l, SA, kdtB);
        chunkU_kernel<<<dim3(BATCH * NCH, DIM / 64), 64, 0, stream>>>(HB, kdtB, U);
        scanP_kernel<<<BATCH * DIM * 4 / 256, 256, 0, stream>>>(U, prm_l, HB);
        apply_gemm_kernel<<<dim3(DIM / 128, BATCH * NCH), 256, 0, stream>>>(SA, HB, Z, Zb);
        gemm_kernel<1><<<dim3(DIM / 128, BNROWS / 128), 256, 0, stream>>>(
            Zb, pwT + (size_t)l * DIM * DIM, k2_pb + (size_t)l * DIM, h, h, nullptr,
            BNROWS, DIM, DIM, DIM);
        rmsnorm_kernel<<<BNROWS, 256, 0, stream>>>(h, k2_n2w + (size_t)l * DIM, hnb);
        const float* nw_next = (l < NL - 1) ? (k2_n1w + (size_t)(l + 1) * DIM) : k1b_nw;
        mlp_core(w1T + (size_t)l * DIM * HID, k2_b1 + (size_t)l * HID,
                 w2T + (size_t)l * HID * DIM, k2_b2 + (size_t)l * DIM, nw_next);
    }

    mlp_core(w1bT, k1b_b1, w2bT, k1b_b2, k0_nw);    // -> hnb = rmsnorm(h, k0_nw)

    // head (4096 x 32000 x 1024)
    gemm256_kernel<0><<<dim3(VOC / 256, BNROWS / 256), 512, 65536, stream>>>(
        hnb, headT, head_b, out, nullptr, BNROWS, VOC, DIM, DIM);
}

// Round 12
// 1499.664 us; speedup vs baseline: 4.0919x; 4.0919x over previous
//
#include <hip/hip_runtime.h>
#include <hip/hip_bf16.h>

#define SEQ 2048
#define DIM 1024
#define RNK 16
#define NL 4
#define KT 7
#define BATCH 2
#define HID 4096
#define VOC 32000
#define BNROWS (BATCH*SEQ)
#define CHK 128
#define NCH (SEQ/CHK)
#define PRMS 128
#define KAPP 160   // apply-GEMM K: 128 (intra) + 16 (inter) + 16 pad

typedef __hip_bfloat16 bf16;
typedef __attribute__((ext_vector_type(8))) short bh8;
typedef __attribute__((ext_vector_type(4))) float vf4;

__device__ __forceinline__ float bfu(unsigned int u) { u <<= 16; return __builtin_bit_cast(float, u); }
__device__ __forceinline__ unsigned short f2bu(float x) { bf16 t = __float2bfloat16(x); return __builtin_bit_cast(unsigned short, t); }
__device__ __forceinline__ float b2f(bf16 x) { return __bfloat162float(x); }
__device__ __forceinline__ float sigm(float x) { return 1.f / (1.f + expf(-x)); }
__device__ __forceinline__ float gelu_t(float x) {
    float u = 0.7978845608028654f * (x + 0.044715f * x * x * x);
    return 0.5f * x * (1.f + tanhf(u));
}

// async global->LDS, 16B per lane. LDS dest = wave-uniform base + lane*16.
__device__ __forceinline__ void gld16(const bf16* g, bf16* l) {
    __builtin_amdgcn_global_load_lds(
        (const __attribute__((address_space(1))) void*)g,
        (__attribute__((address_space(3))) void*)l,
        16, 0, 0);
}

// ---------------- embedding gather ----------------
__global__ void embed_kernel(const int* __restrict__ tokens, const float* __restrict__ emb,
                             float* __restrict__ h) {
    int row = blockIdx.x;
    int tok = tokens[row];
    const float4* src = (const float4*)(emb + (size_t)tok * DIM);
    float4* dst = (float4*)(h + (size_t)row * DIM);
    dst[threadIdx.x] = src[threadIdx.x];
}

// ---------------- rmsnorm -> bf16 ----------------
__global__ void rmsnorm_kernel(const float* __restrict__ in, const float* __restrict__ wt,
                               bf16* __restrict__ out) {
    int row = blockIdx.x;
    int tx = threadIdx.x;
    float4 v = ((const float4*)(in + (size_t)row * DIM))[tx];
    float ss = v.x * v.x + v.y * v.y + v.z * v.z + v.w * v.w;
#pragma unroll
    for (int off = 32; off > 0; off >>= 1) ss += __shfl_down(ss, off);
    __shared__ float red[4];
    int lane = tx & 63, wv = tx >> 6;
    if (lane == 0) red[wv] = ss;
    __syncthreads();
    float tot = red[0] + red[1] + red[2] + red[3];
    float scale = rsqrtf(tot * (1.f / DIM) + 1e-6f);
    float4 w4 = ((const float4*)wt)[tx];
    uint2 o;
    o.x = f2bu(v.x * scale * w4.x) | ((unsigned int)f2bu(v.y * scale * w4.y) << 16);
    o.y = f2bu(v.z * scale * w4.z) | ((unsigned int)f2bu(v.w * scale * w4.w) << 16);
    *(uint2*)(out + (size_t)row * DIM + tx * 4) = o;
}

// ---------------- weight transpose + cast: in (K x Nc) f32 -> out (Nc x K) bf16 ----------------
__global__ void transpose_cast_kernel(const float* __restrict__ in, bf16* __restrict__ out,
                                      int K, int Nc) {
    __shared__ float tile[32][33];
    int n0 = blockIdx.x * 32, k0 = blockIdx.y * 32;
    int tx = threadIdx.x & 31, ty = threadIdx.x >> 5;
#pragma unroll
    for (int i = 0; i < 32; i += 8)
        tile[ty + i][tx] = in[(size_t)(k0 + ty + i) * Nc + n0 + tx];
    __syncthreads();
#pragma unroll
    for (int i = 0; i < 32; i += 8)
        out[(size_t)(n0 + ty + i) * K + k0 + tx] = __float2bfloat16(tile[tx][ty + i]);
}

// ---------------- per-layer params ----------------
__global__ void prep_kernel(const float* __restrict__ dlog, const float* __restrict__ alog,
                            const float* __restrict__ glog, const float* __restrict__ kern,
                            float* __restrict__ prm) {
    int l = blockIdx.x, t = threadIdx.x;
    float* p = prm + l * PRMS;
    if (t < RNK) {
        float g = 0.85f + 0.15f * sigm(dlog[l * RNK + t]);
        float lg = logf(g);
        p[t] = g;
        p[16 + t] = lg;
        p[32 + t] = expf(lg * (float)CHK);
        p[48 + t] = sigm(alog[l * RNK + t]);   // ACAP = 1.0
    }
    if (t < KT) {
        float gate = sigm(glog[l]);
        p[64 + t] = gate * kern[l * KT + t];
    }
}

// ---------------- pack u,v (D x R each) -> uvT (32 x D) bf16 per layer ----------------
__global__ void prep_uv_kernel(const float* __restrict__ u, const float* __restrict__ v,
                               bf16* __restrict__ uvT) {
    int l = blockIdx.y;
    int k = blockIdx.x * 256 + threadIdx.x;
    const float* ul = u + (size_t)l * DIM * RNK;
    const float* vl = v + (size_t)l * DIM * RNK;
    bf16* o = uvT + (size_t)l * 32 * DIM;
#pragma unroll
    for (int r = 0; r < RNK; ++r) {
        o[(size_t)r * DIM + k] = __float2bfloat16(ul[(size_t)k * RNK + r]);
        o[(size_t)(RNK + r) * DIM + k] = __float2bfloat16(vl[(size_t)k * RNK + r]);
    }
}

// ---------------- gated causal conv: Z = gate * conv(hn) ----------------
__global__ void conv_kernel(const bf16* __restrict__ hn, const float* __restrict__ prm,
                            float* __restrict__ Z) {
    int t = blockIdx.x * 256 + threadIdx.x;
    int d4 = (t & 255) * 4;
    int row = t >> 8;
    int n = row & (SEQ - 1);
    float a0 = 0, a1 = 0, a2 = 0, a3 = 0;
#pragma unroll
    for (int kk = 0; kk < KT; ++kk) {
        if (n - kk < 0) break;
        float wv = prm[64 + kk];
        uint2 hv = *(const uint2*)(hn + (size_t)(row - kk) * DIM + d4);
        a0 += wv * bfu(hv.x & 0xffffu);
        a1 += wv * bfu(hv.x >> 16);
        a2 += wv * bfu(hv.y & 0xffffu);
        a3 += wv * bfu(hv.y >> 16);
    }
    float4 o = {a0, a1, a2, a3};
    *(float4*)(Z + (size_t)row * DIM + d4) = o;
}

// ---------------- q/k projection + l2norm via MFMA (16 rows / 1-wave block) ----------------
__global__ __launch_bounds__(64)
void qk_mfma_kernel(const bf16* __restrict__ hn, const bf16* __restrict__ uvT,
                    const float* __restrict__ prm, float* __restrict__ qa,
                    float* __restrict__ kn) {
    int row0 = blockIdx.x * 16;
    int lane = threadIdx.x;
    int fr = lane & 15, kf = (lane >> 4) * 8;
    vf4 accq = {}, acck = {};
#pragma unroll 4
    for (int kt = 0; kt < DIM / 32; ++kt) {
        int k0 = kt * 32;
        bh8 b0 = *(const bh8*)(uvT + (size_t)fr * DIM + k0 + kf);
        bh8 b1 = *(const bh8*)(uvT + (size_t)(16 + fr) * DIM + k0 + kf);
        bh8 a0 = *(const bh8*)(hn + (size_t)(row0 + fr) * DIM + k0 + kf);
        accq = __builtin_amdgcn_mfma_f32_16x16x32_bf16(a0, b0, accq, 0, 0, 0);
        acck = __builtin_amdgcn_mfma_f32_16x16x32_bf16(a0, b1, acck, 0, 0, 0);
    }
    int fq = lane >> 4;
    float alpha = prm[48 + fr];
#pragma unroll
    for (int j = 0; j < 4; ++j) {
        float qv = accq[j], kv = acck[j];
        float sq = qv * qv, sk = kv * kv;
#pragma unroll
        for (int mask = 1; mask < 16; mask <<= 1) {
            sq += __shfl_xor(sq, mask);
            sk += __shfl_xor(sk, mask);
        }
        int row = row0 + fq * 4 + j;
        qa[(size_t)row * RNK + fr] = qv / fmaxf(sqrtf(sq), 1e-8f) * alpha;
        kn[(size_t)row * RNK + fr] = kv / fmaxf(sqrtf(sk), 1e-8f);
    }
}

// ---------------- per-chunk transpose of hn into HB[bc][d][0..128) ----------------
__global__ void trans_hn_kernel(const bf16* __restrict__ hn, bf16* __restrict__ HB) {
    __shared__ bf16 tile[32][40];
    int bc = blockIdx.x;
    int d0 = blockIdx.y * 32, j0 = blockIdx.z * 32;
    int tx = threadIdx.x & 31, ty = threadIdx.x >> 5;
    size_t rowb = (size_t)bc * CHK;
#pragma unroll
    for (int i = 0; i < 32; i += 8)
        tile[ty + i][tx] = hn[(rowb + j0 + ty + i) * DIM + d0 + tx];
    __syncthreads();
    bf16* Hp = HB + (size_t)bc * DIM * KAPP;
#pragma unroll
    for (int i = 0; i < 32; i += 8)
        Hp[(size_t)(d0 + ty + i) * KAPP + j0 + tx] = tile[tx][ty + i];
}

// ---------------- scores + apply-A assembly + kdt (split over i-tiles) ----------------
__global__ void scores_kernel(const float* __restrict__ qa, const float* __restrict__ kn,
                              const float* __restrict__ prm, bf16* __restrict__ SA,
                              bf16* __restrict__ kdtB) {
    int bc = blockIdx.x;
    int yt = blockIdx.y;
    __shared__ float ptab[CHK][16];
    for (int e = threadIdx.x; e < CHK * 16; e += 256) {
        int tt = e >> 4, r = e & 15;
        ptab[tt][r] = expf(prm[16 + r] * (float)tt);
    }
    __syncthreads();
    size_t rowb = (size_t)bc * CHK;
    bf16* SAp = SA + (size_t)bc * CHK * KAPP;
    for (int e = threadIdx.x; e < 16 * CHK; e += 256) {
        int i = yt * 16 + (e >> 7), j = e & (CHK - 1);
        float vsum = 0.f;
        if (i >= j) {
            const float* qp = qa + (rowb + i) * RNK;
            const float* kp = kn + (rowb + j) * RNK;
#pragma unroll
            for (int r = 0; r < 16; ++r) vsum += qp[r] * ptab[i - j][r] * kp[r];
        }
        SAp[(size_t)i * KAPP + j] = __float2bfloat16(vsum);
    }
    for (int e = threadIdx.x; e < 16 * 32; e += 256) {
        int i = yt * 16 + (e >> 5), rr = e & 31;
        float w = 0.f;
        if (rr < 16) w = qa[(rowb + i) * RNK + rr] * expf(prm[16 + rr] * (float)(i + 1));
        SAp[(size_t)i * KAPP + CHK + rr] = __float2bfloat16(w);
    }
    bf16* kp2 = kdtB + (size_t)bc * RNK * CHK;
    for (int e = threadIdx.x; e < 2 * CHK; e += 256) {
        int r = 2 * yt + (e >> 7), j = e & (CHK - 1);
        kp2[(size_t)r * CHK + j] =
            __float2bfloat16(ptab[CHK - 1 - j][r] * kn[(rowb + j) * RNK + r]);
    }
}

// ---------------- chunkU via MFMA ----------------
__global__ __launch_bounds__(64)
void chunkU_kernel(const bf16* __restrict__ HB, const bf16* __restrict__ kdtB,
                   float* __restrict__ U) {
    int bc = blockIdx.x;
    int d0 = blockIdx.y * 64;
    int lane = threadIdx.x;
    int fr = lane & 15, kf = (lane >> 4) * 8;
    const bf16* Hp = HB + (size_t)bc * DIM * KAPP;
    const bf16* Kp = kdtB + (size_t)bc * RNK * CHK;
    vf4 acc[4] = {};
#pragma unroll
    for (int kt = 0; kt < 4; ++kt) {
        int k0 = kt * 32;
        bh8 bb = *(const bh8*)(Kp + (size_t)fr * CHK + k0 + kf);
#pragma unroll
        for (int m = 0; m < 4; ++m) {
            bh8 a = *(const bh8*)(Hp + (size_t)(d0 + m * 16 + fr) * KAPP + k0 + kf);
            acc[m] = __builtin_amdgcn_mfma_f32_16x16x32_bf16(a, bb, acc[m], 0, 0, 0);
        }
    }
    int fq = lane >> 4;
    float* Up = U + (size_t)bc * DIM * RNK;
#pragma unroll
    for (int m = 0; m < 4; ++m)
#pragma unroll
        for (int j = 0; j < 4; ++j)
            Up[(size_t)(d0 + m * 16 + fq * 4 + j) * RNK + fr] = acc[m][j];
}

// ---------------- chunk scan: P^T bf16 into HB[bc][d][128..144), 4 ranks/thread ----------------
__global__ void scanP_kernel(const float* __restrict__ U, const float* __restrict__ prm,
                             bf16* __restrict__ HB) {
    int g = blockIdx.x * 256 + threadIdx.x;
    int rq = g & 3;
    int d = (g >> 2) & (DIM - 1);
    int b = g >> 12;
    float gC[4], p[4];
#pragma unroll
    for (int q = 0; q < 4; ++q) { gC[q] = prm[32 + rq * 4 + q]; p[q] = 0.f; }
    for (int c = 0; c < NCH; ++c) {
        int bc = b * NCH + c;
        uint2 pk;
        pk.x = (unsigned int)f2bu(p[0]) | ((unsigned int)f2bu(p[1]) << 16);
        pk.y = (unsigned int)f2bu(p[2]) | ((unsigned int)f2bu(p[3]) << 16);
        *(uint2*)(HB + (size_t)bc * DIM * KAPP + (size_t)d * KAPP + CHK + rq * 4) = pk;
        float4 u4 = *(const float4*)(U + ((size_t)bc * DIM + d) * RNK + rq * 4);
        p[0] = gC[0] * p[0] + u4.x;
        p[1] = gC[1] * p[1] + u4.y;
        p[2] = gC[2] * p[2] + u4.z;
        p[3] = gC[3] * p[3] + u4.w;
    }
}

// ---------------- apply GEMM: Zb = bf16( Z + SA[bc] @ HB[bc]^T ) ----------------
__global__ __launch_bounds__(256)
void apply_gemm_kernel(const bf16* __restrict__ SA, const bf16* __restrict__ HB,
                       const float* __restrict__ Z, bf16* __restrict__ Zb) {
    __shared__ alignas(16) bf16 As[128][40];
    __shared__ alignas(16) bf16 Bs[128][40];
    int bc = blockIdx.y;
    int colB0 = blockIdx.x * 128;
    int t = threadIdx.x;
    int lane = t & 63, wid = t >> 6;
    int wr = wid >> 1, wc = wid & 1;
    vf4 acc[4][4] = {};
    const bf16* A = SA + (size_t)bc * CHK * KAPP;
    const bf16* BT = HB + (size_t)bc * DIM * KAPP;
    int r1 = t >> 2, ko1 = (t & 3) * 8;
    int fr = lane & 15, kf = (lane >> 4) * 8;
#pragma unroll
    for (int kt = 0; kt < 5; ++kt) {
        int k0 = kt * 32;
        int4 va1 = *(const int4*)(A + (size_t)r1 * KAPP + k0 + ko1);
        int4 va2 = *(const int4*)(A + (size_t)(r1 + 64) * KAPP + k0 + ko1);
        int4 vb1 = *(const int4*)(BT + (size_t)(colB0 + r1) * KAPP + k0 + ko1);
        int4 vb2 = *(const int4*)(BT + (size_t)(colB0 + r1 + 64) * KAPP + k0 + ko1);
        __syncthreads();
        *(int4*)&As[r1][ko1] = va1;
        *(int4*)&As[r1 + 64][ko1] = va2;
        *(int4*)&Bs[r1][ko1] = vb1;
        *(int4*)&Bs[r1 + 64][ko1] = vb2;
        __syncthreads();
        bh8 a[4], bb[4];
#pragma unroll
        for (int m = 0; m < 4; ++m) a[m] = *(const bh8*)&As[wr * 64 + m * 16 + fr][kf];
#pragma unroll
        for (int n = 0; n < 4; ++n) bb[n] = *(const bh8*)&Bs[wc * 64 + n * 16 + fr][kf];
#pragma unroll
        for (int m = 0; m < 4; ++m)
#pragma unroll
            for (int n = 0; n < 4; ++n)
                acc[m][n] = __builtin_amdgcn_mfma_f32_16x16x32_bf16(a[m], bb[n], acc[m][n], 0, 0, 0);
    }
    int fq = lane >> 4;
    size_t rowb = (size_t)bc * CHK;
#pragma unroll
    for (int m = 0; m < 4; ++m) {
#pragma unroll
        for (int n = 0; n < 4; ++n) {
            int col = colB0 + wc * 64 + n * 16 + fr;
#pragma unroll
            for (int j = 0; j < 4; ++j) {
                size_t row = rowb + wr * 64 + m * 16 + fq * 4 + j;
                size_t idx = row * DIM + col;
                Zb[idx] = __float2bfloat16(Z[idx] + acc[m][n][j]);
            }
        }
    }
}

// ---------------- 128-tile m97-structure GEMM (lda-parameterized) ----------------
// EPI 1: out = res + acc + bias (f32, in-place)
template <int EPI>
__global__ __launch_bounds__(256)
void gemm_kernel(const bf16* __restrict__ A, const bf16* __restrict__ BT,
                 const float* __restrict__ bias, const float* __restrict__ res,
                 float* __restrict__ outF, bf16* __restrict__ outB,
                 int M, int Nc, int K, int lda) {
    __shared__ alignas(16) bf16 As[128][32];
    __shared__ alignas(16) bf16 Bs[128][32];
    int gx = gridDim.x;
    int orig = blockIdx.y * gx + blockIdx.x;
    int qch = (gx * gridDim.y) >> 3;
    int wg = (orig & 7) * qch + (orig >> 3);
    int bn = wg % gx, bm = wg / gx;
    int t = threadIdx.x;
    int lane = t & 63, wid = t >> 6;
    int wr = wid >> 1, wc = wid & 1;
    vf4 acc[4][4] = {};
    const int rowA0 = bm * 128, colB0 = bn * 128;
    int fr = lane & 15, kf = (lane >> 4) * 8;
    int c0 = wid * 2;
    int lrow = lane >> 2;
    int lcol = (lane & 3) * 8;
    const bf16* Ag0 = A + (size_t)(rowA0 + c0 * 16 + lrow) * lda + lcol;
    const bf16* Ag1 = A + (size_t)(rowA0 + c0 * 16 + 16 + lrow) * lda + lcol;
    const bf16* Bg0 = BT + (size_t)(colB0 + c0 * 16 + lrow) * lda + lcol;
    const bf16* Bg1 = BT + (size_t)(colB0 + c0 * 16 + 16 + lrow) * lda + lcol;
    bf16* Al0 = &As[0][0] + c0 * 512;
    bf16* Al1 = Al0 + 512;
    bf16* Bl0 = &Bs[0][0] + c0 * 512;
    bf16* Bl1 = Bl0 + 512;
    int nk = K >> 5;
    for (int kt = 0; kt < nk; ++kt) {
        int k0 = kt * 32;
        __syncthreads();
        gld16(Ag0 + k0, Al0);
        gld16(Ag1 + k0, Al1);
        gld16(Bg0 + k0, Bl0);
        gld16(Bg1 + k0, Bl1);
        asm volatile("s_waitcnt vmcnt(0)" ::: "memory");
        __syncthreads();
        bh8 a[4], bb[4];
#pragma unroll
        for (int m = 0; m < 4; ++m) a[m] = *(const bh8*)&As[wr * 64 + m * 16 + fr][kf];
#pragma unroll
        for (int n = 0; n < 4; ++n) bb[n] = *(const bh8*)&Bs[wc * 64 + n * 16 + fr][kf];
#pragma unroll
        for (int m = 0; m < 4; ++m)
#pragma unroll
            for (int n = 0; n < 4; ++n)
                acc[m][n] = __builtin_amdgcn_mfma_f32_16x16x32_bf16(a[m], bb[n], acc[m][n], 0, 0, 0);
    }
    int fq = lane >> 4;
#pragma unroll
    for (int m = 0; m < 4; ++m) {
#pragma unroll
        for (int n = 0; n < 4; ++n) {
            int col = colB0 + wc * 64 + n * 16 + fr;
            float bv = bias[col];
#pragma unroll
            for (int j = 0; j < 4; ++j) {
                int row = rowA0 + wr * 64 + m * 16 + fq * 4 + j;
                size_t idx = (size_t)row * Nc + col;
                float v2 = acc[m][n][j] + bv;
                if (EPI == 1) v2 += res[idx];
                outF[idx] = v2;
            }
        }
    }
}

// ---------------- 256-tile 2-phase GEMM (r10 proven config: BK=64, 128 KiB, 1 blk/CU) ----------------
// Per K-tile (BK=64): P0 {stage B(nd) x4 loads; vmcnt(4); barrier; ds_read A m0-3 + B (both
// kk); 32 MFMA acc[0..3]}; P1 {stage A(nd) x4; barrier; ds_read A m4-7; 32 MFMA acc[4..7]}.
// NOTE r11 lesson: acc[8][4]=128 VGPR/lane caps this tile at 2 waves/SIMD — do NOT set
// min-waves=4 (forces 128-reg cap -> accumulator spill -> 11 GB scratch traffic, 4x slower).
// EPI 0: f32 out+bias (regular store — NT caused 40% write amplification, r9);
// EPI 2: bf16 gelu(out+bias); EPI 4: bf16 split-K partial
#define SB __builtin_amdgcn_sched_barrier(0)
template <int EPI>
__global__ __launch_bounds__(512, 2)
void gemm256_kernel(const bf16* __restrict__ A, const bf16* __restrict__ BT,
                    const float* __restrict__ bias,
                    float* __restrict__ outF, bf16* __restrict__ outB,
                    int M, int Nc, int K, int lda) {
    extern __shared__ char smem[];
    bf16* Alds = (bf16*)smem;             // 2dbuf x 2kh x 8192 elems
    bf16* Blds = (bf16*)(smem + 65536);
    if (EPI == 4) {
        size_t zo = (size_t)blockIdx.z * K;
        A += zo; BT += zo;
        outB += (size_t)blockIdx.z * ((size_t)M * Nc);
    }
    int gx = gridDim.x, gy = gridDim.y;
    int orig = blockIdx.y * gx + blockIdx.x;
    int qch = (gx * gy) >> 3;
    int wg = (orig & 7) * qch + (orig >> 3);
    int bm = wg % gy, bn = wg / gy;   // column-major: XCD chunk shares bn panels
    int rowA0 = bm * 256, colB0 = bn * 256;
    int tid = threadIdx.x;
    int lane = tid & 63, wid = tid >> 6;
    int wm = wid >> 2, wn = wid & 3;
    int fr = lane & 15;
    int kf8 = ((((lane >> 4) & 3) ^ ((fr >> 1) & 3)) * 8);
    int srow = wid * 16 + (lane >> 2);
    int scol = (((lane & 3) ^ ((lane >> 3) & 3)) * 8);
    const bf16* Ags = A + (size_t)(rowA0 + srow) * lda + scol;
    const bf16* Bgs = BT + (size_t)(colB0 + srow) * lda + scol;
    int sbase = wid * 512;
    auto stA = [&](int d, int kh, int k0) {
        bf16* dst = Alds + (d * 2 + kh) * 8192 + sbase;
        const bf16* src = Ags + k0 + kh * 32;
        gld16(src, dst);
        gld16(src + (size_t)128 * lda, dst + 4096);
    };
    auto stB = [&](int d, int kh, int k0) {
        bf16* dst = Blds + (d * 2 + kh) * 8192 + sbase;
        const bf16* src = Bgs + k0 + kh * 32;
        gld16(src, dst);
        gld16(src + (size_t)128 * lda, dst + 4096);
    };
    const bf16* Ard = Alds + (size_t)(wm * 128 + fr) * 32 + kf8;
    const bf16* Brd = Blds + (size_t)(wn * 64 + fr) * 32 + kf8;
    vf4 acc[8][4] = {};
    int ntk = K >> 6;
    // prologue: B then A of tile 0 -> queue [B0 x4, A0 x4]
    stB(0, 0, 0); stB(0, 1, 0); stA(0, 0, 0); stA(0, 1, 0);
    for (int t = 0; t < ntk; ++t) {
        int d = t & 1, nd = d ^ 1;
        int k1 = (t + 1) << 6;
        bool pf = (t + 1 < ntk);
        int dof = d * 16384;          // kh0 of dbuf d
        int dof1 = dof + 8192;        // kh1
        bh8 bF0[4], bF1[4];
        // ---- P0: stage B(nd), wait buf d, read A m0-3 + B (kk0,kk1), MFMA acc[0..3] ----
        if (pf) { stB(nd, 0, k1); stB(nd, 1, k1);
                  asm volatile("s_waitcnt vmcnt(4)" ::: "memory"); }
        else    { asm volatile("s_waitcnt vmcnt(0)" ::: "memory"); }
        SB; __builtin_amdgcn_s_barrier(); SB;
        {
            bh8 a00 = *(const bh8*)(Ard + dof + 0 * 512);
            bh8 a01 = *(const bh8*)(Ard + dof + 1 * 512);
            bh8 a02 = *(const bh8*)(Ard + dof + 2 * 512);
            bh8 a03 = *(const bh8*)(Ard + dof + 3 * 512);
            bh8 a10 = *(const bh8*)(Ard + dof1 + 0 * 512);
            bh8 a11 = *(const bh8*)(Ard + dof1 + 1 * 512);
            bh8 a12 = *(const bh8*)(Ard + dof1 + 2 * 512);
            bh8 a13 = *(const bh8*)(Ard + dof1 + 3 * 512);
#pragma unroll
            for (int n = 0; n < 4; ++n) {
                bF0[n] = *(const bh8*)(Brd + dof + n * 512);
                bF1[n] = *(const bh8*)(Brd + dof1 + n * 512);
            }
            __builtin_amdgcn_s_setprio(1);
#pragma unroll
            for (int n = 0; n < 4; ++n) {
                acc[0][n] = __builtin_amdgcn_mfma_f32_16x16x32_bf16(a00, bF0[n], acc[0][n], 0, 0, 0);
                acc[1][n] = __builtin_amdgcn_mfma_f32_16x16x32_bf16(a01, bF0[n], acc[1][n], 0, 0, 0);
                acc[2][n] = __builtin_amdgcn_mfma_f32_16x16x32_bf16(a02, bF0[n], acc[2][n], 0, 0, 0);
                acc[3][n] = __builtin_amdgcn_mfma_f32_16x16x32_bf16(a03, bF0[n], acc[3][n], 0, 0, 0);
            }
#pragma unroll
            for (int n = 0; n < 4; ++n) {
                acc[0][n] = __builtin_amdgcn_mfma_f32_16x16x32_bf16(a10, bF1[n], acc[0][n], 0, 0, 0);
                acc[1][n] = __builtin_amdgcn_mfma_f32_16x16x32_bf16(a11, bF1[n], acc[1][n], 0, 0, 0);
                acc[2][n] = __builtin_amdgcn_mfma_f32_16x16x32_bf16(a12, bF1[n], acc[2][n], 0, 0, 0);
                acc[3][n] = __builtin_amdgcn_mfma_f32_16x16x32_bf16(a13, bF1[n], acc[3][n], 0, 0, 0);
            }
            __builtin_amdgcn_s_setprio(0);
        }
        SB;
        // ---- P1: stage A(nd), barrier, read A m4-7 (kk0,kk1), MFMA acc[4..7] ----
        if (pf) { stA(nd, 0, k1); stA(nd, 1, k1); }
        SB; __builtin_amdgcn_s_barrier(); SB;
        {
            bh8 a00 = *(const bh8*)(Ard + dof + 4 * 512);
            bh8 a01 = *(const bh8*)(Ard + dof + 5 * 512);
            bh8 a02 = *(const bh8*)(Ard + dof + 6 * 512);
            bh8 a03 = *(const bh8*)(Ard + dof + 7 * 512);
            bh8 a10 = *(const bh8*)(Ard + dof1 + 4 * 512);
            bh8 a11 = *(const bh8*)(Ard + dof1 + 5 * 512);
            bh8 a12 = *(const bh8*)(Ard + dof1 + 6 * 512);
            bh8 a13 = *(const bh8*)(Ard + dof1 + 7 * 512);
            __builtin_amdgcn_s_setprio(1);
#pragma unroll
            for (int n = 0; n < 4; ++n) {
                acc[4][n] = __builtin_amdgcn_mfma_f32_16x16x32_bf16(a00, bF0[n], acc[4][n], 0, 0, 0);
                acc[5][n] = __builtin_amdgcn_mfma_f32_16x16x32_bf16(a01, bF0[n], acc[5][n], 0, 0, 0);
                acc[6][n] = __builtin_amdgcn_mfma_f32_16x16x32_bf16(a02, bF0[n], acc[6][n], 0, 0, 0);
                acc[7][n] = __builtin_amdgcn_mfma_f32_16x16x32_bf16(a03, bF0[n], acc[7][n], 0, 0, 0);
            }
#pragma unroll
            for (int n = 0; n < 4; ++n) {
                acc[4][n] = __builtin_amdgcn_mfma_f32_16x16x32_bf16(a10, bF1[n], acc[4][n], 0, 0, 0);
                acc[5][n] = __builtin_amdgcn_mfma_f32_16x16x32_bf16(a11, bF1[n], acc[5][n], 0, 0, 0);
                acc[6][n] = __builtin_amdgcn_mfma_f32_16x16x32_bf16(a12, bF1[n], acc[6][n], 0, 0, 0);
                acc[7][n] = __builtin_amdgcn_mfma_f32_16x16x32_bf16(a13, bF1[n], acc[7][n], 0, 0, 0);
            }
            __builtin_amdgcn_s_setprio(0);
        }
        SB;
    }
    int fq = lane >> 4;
#pragma unroll
    for (int mi = 0; mi < 8; ++mi) {
#pragma unroll
        for (int ni = 0; ni < 4; ++ni) {
            int col = colB0 + wn * 64 + ni * 16 + fr;
            float bv = (EPI == 4) ? 0.f : bias[col];
#pragma unroll
            for (int j = 0; j < 4; ++j) {
                int row = rowA0 + wm * 128 + mi * 16 + fq * 4 + j;
                size_t idx = (size_t)row * Nc + col;
                float v2 = acc[mi][ni][j] + bv;
                if (EPI == 2) outB[idx] = __float2bfloat16(gelu_t(v2));
                else if (EPI == 4) outB[idx] = __float2bfloat16(v2);
                else outF[idx] = v2;
            }
        }
    }
}

// ---------------- fused split-K combine (bf16 partials) + rmsnorm ----------------
__global__ void combine4_norm_kernel(const bf16* __restrict__ P, const float* __restrict__ bias,
                                     const float* __restrict__ nw, float* __restrict__ h,
                                     bf16* __restrict__ hnb) {
    int row = blockIdx.x;
    int tx = threadIdx.x;
    const size_t S = (size_t)BNROWS * DIM;
    size_t base = (size_t)row * DIM + tx * 4;
    float4 hv = *(float4*)(h + base);
    float4 bv = ((const float4*)bias)[tx];
    float s0 = bv.x, s1 = bv.y, s2 = bv.z, s3 = bv.w;
#pragma unroll
    for (int q = 0; q < 4; ++q) {
        uint2 pk = *(const uint2*)(P + q * S + base);
        s0 += bfu(pk.x & 0xffffu);
        s1 += bfu(pk.x >> 16);
        s2 += bfu(pk.y & 0xffffu);
        s3 += bfu(pk.y >> 16);
    }
    hv.x += s0; hv.y += s1; hv.z += s2; hv.w += s3;
    *(float4*)(h + base) = hv;
    float ss = hv.x * hv.x + hv.y * hv.y + hv.z * hv.z + hv.w * hv.w;
#pragma unroll
    for (int off = 32; off > 0; off >>= 1) ss += __shfl_down(ss, off);
    __shared__ float red[4];
    int lane = tx & 63, wv = tx >> 6;
    if (lane == 0) red[wv] = ss;
    __syncthreads();
    float tot = red[0] + red[1] + red[2] + red[3];
    float scale = rsqrtf(tot * (1.f / DIM) + 1e-6f);
    float4 w4 = ((const float4*)nw)[tx];
    uint2 o;
    o.x = f2bu(hv.x * scale * w4.x) | ((unsigned int)f2bu(hv.y * scale * w4.y) << 16);
    o.y = f2bu(hv.z * scale * w4.z) | ((unsigned int)f2bu(hv.w * scale * w4.w) << 16);
    *(uint2*)(hnb + (size_t)row * DIM + tx * 4) = o;
}

// ===================================================================
extern "C" void kernel_launch(void* const* d_in, const int* in_sizes, int n_in,
                              void* d_out, int out_size, void* d_ws, size_t ws_size,
                              hipStream_t stream) {
    (void)in_sizes; (void)n_in; (void)out_size; (void)ws_size;
    const int* tokens = (const int*)d_in[0];
    const float* emb = (const float*)d_in[1];
    const float* k1a_nw = (const float*)d_in[2];
    const float* k1a_w1 = (const float*)d_in[3];
    const float* k1a_b1 = (const float*)d_in[4];
    const float* k1a_w2 = (const float*)d_in[5];
    const float* k1a_b2 = (const float*)d_in[6];
    const float* k2_u = (const float*)d_in[7];
    const float* k2_v = (const float*)d_in[8];
    const float* k2_dlog = (const float*)d_in[9];
    const float* k2_alog = (const float*)d_in[10];
    const float* k2_glog = (const float*)d_in[11];
    const float* k2_kern = (const float*)d_in[12];
    const float* k2_pw = (const float*)d_in[13];
    const float* k2_pb = (const float*)d_in[14];
    const float* k2_n1w = (const float*)d_in[15];
    const float* k2_n2w = (const float*)d_in[16];
    const float* k2_w1 = (const float*)d_in[17];
    const float* k2_b1 = (const float*)d_in[18];
    const float* k2_w2 = (const float*)d_in[19];
    const float* k2_b2 = (const float*)d_in[20];
    const float* k1b_nw = (const float*)d_in[21];
    const float* k1b_w1 = (const float*)d_in[22];
    const float* k1b_b1 = (const float*)d_in[23];
    const float* k1b_w2 = (const float*)d_in[24];
    const float* k1b_b2 = (const float*)d_in[25];
    const float* k0_nw = (const float*)d_in[26];
    const float* head_w = (const float*)d_in[27];
    const float* head_b = (const float*)d_in[28];
    float* out = (float*)d_out;

    (void)hipFuncSetAttribute((const void*)gemm256_kernel<0>,
                              hipFuncAttributeMaxDynamicSharedMemorySize, 131072);
    (void)hipFuncSetAttribute((const void*)gemm256_kernel<2>,
                              hipFuncAttributeMaxDynamicSharedMemorySize, 131072);
    (void)hipFuncSetAttribute((const void*)gemm256_kernel<4>,
                              hipFuncAttributeMaxDynamicSharedMemorySize, 131072);

    // ---- workspace carve ----
    char* wsp = (char*)d_ws;
    auto alloc = [&](size_t bytes) -> char* {
        char* p = wsp;
        wsp += (bytes + 255) & ~(size_t)255;
        return p;
    };
    float* h   = (float*)alloc((size_t)BNROWS * DIM * 4);
    float* Z   = (float*)alloc((size_t)BNROWS * DIM * 4);
    bf16* hnb  = (bf16*)alloc((size_t)BNROWS * DIM * 2);
    bf16* Zb   = (bf16*)alloc((size_t)BNROWS * DIM * 2);
    bf16* t1b  = (bf16*)alloc((size_t)BNROWS * HID * 2);
    float* qaB = (float*)alloc((size_t)BNROWS * RNK * 4);
    float* knB = (float*)alloc((size_t)BNROWS * RNK * 4);
    float* U   = (float*)alloc((size_t)BATCH * NCH * DIM * RNK * 4);
    bf16* HB   = (bf16*)alloc((size_t)BATCH * NCH * DIM * KAPP * 2);
    bf16* SA   = (bf16*)alloc((size_t)BATCH * NCH * CHK * KAPP * 2);
    bf16* kdtB = (bf16*)alloc((size_t)BATCH * NCH * RNK * CHK * 2);
    float* prm = (float*)alloc((size_t)NL * PRMS * 4);
    bf16* uvT  = (bf16*)alloc((size_t)NL * 32 * DIM * 2);
    bf16* w1aT = (bf16*)alloc((size_t)HID * DIM * 2);
    bf16* w2aT = (bf16*)alloc((size_t)DIM * HID * 2);
    bf16* w1bT = (bf16*)alloc((size_t)HID * DIM * 2);
    bf16* w2bT = (bf16*)alloc((size_t)DIM * HID * 2);
    bf16* pwT  = (bf16*)alloc((size_t)NL * DIM * DIM * 2);
    bf16* w1T  = (bf16*)alloc((size_t)NL * DIM * HID * 2);
    bf16* w2T  = (bf16*)alloc((size_t)NL * HID * DIM * 2);
    bf16* headT = (bf16*)alloc((size_t)VOC * DIM * 2);
    bf16* Pk  = (bf16*)alloc((size_t)4 * BNROWS * DIM * 2);   // split-K partials (bf16)

    hipMemsetAsync(HB, 0, (size_t)BATCH * NCH * DIM * KAPP * 2, stream);

    auto T = [&](const float* in, bf16* o, int K, int Nc) {
        transpose_cast_kernel<<<dim3(Nc / 32, K / 32), 256, 0, stream>>>(in, o, K, Nc);
    };
    // ---- weight prep ----
    T(k1a_w1, w1aT, DIM, HID);
    T(k1a_w2, w2aT, HID, DIM);
    T(k1b_w1, w1bT, DIM, HID);
    T(k1b_w2, w2bT, HID, DIM);
    for (int l = 0; l < NL; ++l) {
        T(k2_pw + (size_t)l * DIM * DIM, pwT + (size_t)l * DIM * DIM, DIM, DIM);
        T(k2_w1 + (size_t)l * DIM * HID, w1T + (size_t)l * DIM * HID, DIM, HID);
        T(k2_w2 + (size_t)l * HID * DIM, w2T + (size_t)l * HID * DIM, HID, DIM);
    }
    T(head_w, headT, DIM, VOC);
    prep_kernel<<<NL, 32, 0, stream>>>(k2_dlog, k2_alog, k2_glog, k2_kern, prm);
    prep_uv_kernel<<<dim3(DIM / 256, NL), 256, 0, stream>>>(k2_u, k2_v, uvT);

    // mlp core: assumes hnb holds rmsnorm of h; leaves h updated and hnb = rmsnorm(h, nw_next)
    auto mlp_core = [&](const bf16* W1, const float* B1, const bf16* W2, const float* B2,
                        const float* nw_next) {
        gemm256_kernel<2><<<dim3(HID / 256, BNROWS / 256), 512, 131072, stream>>>(
            hnb, W1, B1, nullptr, t1b, BNROWS, HID, DIM, DIM);
        gemm256_kernel<4><<<dim3(DIM / 256, BNROWS / 256, 4), 512, 131072, stream>>>(
            t1b, W2, nullptr, nullptr, Pk, BNROWS, DIM, HID / 4, HID);
        combine4_norm_kernel<<<BNROWS, 256, 0, stream>>>(Pk, B2, nw_next, h, hnb);
    };

    // ---- forward ----
    embed_kernel<<<BNROWS, 256, 0, stream>>>(tokens, emb, h);
    rmsnorm_kernel<<<BNROWS, 256, 0, stream>>>(h, k1a_nw, hnb);
    mlp_core(w1aT, k1a_b1, w2aT, k1a_b2, k2_n1w);   // -> hnb = rmsnorm(h, n1w[0])

    for (int l = 0; l < NL; ++l) {
        const float* prm_l = prm + l * PRMS;
        conv_kernel<<<BNROWS, 256, 0, stream>>>(hnb, prm_l, Z);
        qk_mfma_kernel<<<BNROWS / 16, 64, 0, stream>>>(hnb, uvT + (size_t)l * 32 * DIM,
                                                       prm_l, qaB, knB);
        trans_hn_kernel<<<dim3(BATCH * NCH, DIM / 32, CHK / 32), 256, 0, stream>>>(hnb, HB);
        scores_kernel<<<dim3(BATCH * NCH, 8), 256, 0, stream>>>(qaB, knB, prm_l, SA, kdtB);
        chunkU_kernel<<<dim3(BATCH * NCH, DIM / 64), 64, 0, stream>>>(HB, kdtB, U);
        scanP_kernel<<<BATCH * DIM * 4 / 256, 256, 0, stream>>>(U, prm_l, HB);
        apply_gemm_kernel<<<dim3(DIM / 128, BATCH * NCH), 256, 0, stream>>>(SA, HB, Z, Zb);
        gemm_kernel<1><<<dim3(DIM / 128, BNROWS / 128), 256, 0, stream>>>(
            Zb, pwT + (size_t)l * DIM * DIM, k2_pb + (size_t)l * DIM, h, h, nullptr,
            BNROWS, DIM, DIM, DIM);
        rmsnorm_kernel<<<BNROWS, 256, 0, stream>>>(h, k2_n2w + (size_t)l * DIM, hnb);
        const float* nw_next = (l < NL - 1) ? (k2_n1w + (size_t)(l + 1) * DIM) : k1b_nw;
        mlp_core(w1T + (size_t)l * DIM * HID, k2_b1 + (size_t)l * HID,
                 w2T + (size_t)l * HID * DIM, k2_b2 + (size_t)l * DIM, nw_next);
    }

    mlp_core(w1bT, k1b_b1, w2bT, k1b_b2, k0_nw);    // -> hnb = rmsnorm(h, k0_nw)

    // head (4096 x 32000 x 1024)
    gemm256_kernel<0><<<dim3(VOC / 256, BNROWS / 256), 512, 131072, stream>>>(
        hnb, headT, head_b, out, nullptr, BNROWS, VOC, DIM, DIM);
}

// Round 13
// 1447.980 us; speedup vs baseline: 4.2380x; 1.0357x over previous
//
#include <hip/hip_runtime.h>
#include <hip/hip_bf16.h>

#define SEQ 2048
#define DIM 1024
#define RNK 16
#define NL 4
#define KT 7
#define BATCH 2
#define HID 4096
#define VOC 32000
#define BNROWS (BATCH*SEQ)
#define CHK 128
#define NCH (SEQ/CHK)
#define PRMS 128
#define KAPP 160   // apply-GEMM K: 128 (intra) + 16 (inter) + 16 pad

typedef __hip_bfloat16 bf16;
typedef __attribute__((ext_vector_type(8))) short bh8;
typedef __attribute__((ext_vector_type(4))) float vf4;

__device__ __forceinline__ float bfu(unsigned int u) { u <<= 16; return __builtin_bit_cast(float, u); }
__device__ __forceinline__ unsigned short f2bu(float x) { bf16 t = __float2bfloat16(x); return __builtin_bit_cast(unsigned short, t); }
__device__ __forceinline__ float b2f(bf16 x) { return __bfloat162float(x); }
__device__ __forceinline__ float sigm(float x) { return 1.f / (1.f + expf(-x)); }
__device__ __forceinline__ float gelu_t(float x) {
    float u = 0.7978845608028654f * (x + 0.044715f * x * x * x);
    return 0.5f * x * (1.f + tanhf(u));
}

// async global->LDS, 16B per lane. LDS dest = wave-uniform base + lane*16.
__device__ __forceinline__ void gld16(const bf16* g, bf16* l) {
    __builtin_amdgcn_global_load_lds(
        (const __attribute__((address_space(1))) void*)g,
        (__attribute__((address_space(3))) void*)l,
        16, 0, 0);
}

// ---------------- embedding gather ----------------
__global__ void embed_kernel(const int* __restrict__ tokens, const float* __restrict__ emb,
                             float* __restrict__ h) {
    int row = blockIdx.x;
    int tok = tokens[row];
    const float4* src = (const float4*)(emb + (size_t)tok * DIM);
    float4* dst = (float4*)(h + (size_t)row * DIM);
    dst[threadIdx.x] = src[threadIdx.x];
}

// ---------------- rmsnorm -> bf16 ----------------
__global__ void rmsnorm_kernel(const float* __restrict__ in, const float* __restrict__ wt,
                               bf16* __restrict__ out) {
    int row = blockIdx.x;
    int tx = threadIdx.x;
    float4 v = ((const float4*)(in + (size_t)row * DIM))[tx];
    float ss = v.x * v.x + v.y * v.y + v.z * v.z + v.w * v.w;
#pragma unroll
    for (int off = 32; off > 0; off >>= 1) ss += __shfl_down(ss, off);
    __shared__ float red[4];
    int lane = tx & 63, wv = tx >> 6;
    if (lane == 0) red[wv] = ss;
    __syncthreads();
    float tot = red[0] + red[1] + red[2] + red[3];
    float scale = rsqrtf(tot * (1.f / DIM) + 1e-6f);
    float4 w4 = ((const float4*)wt)[tx];
    uint2 o;
    o.x = f2bu(v.x * scale * w4.x) | ((unsigned int)f2bu(v.y * scale * w4.y) << 16);
    o.y = f2bu(v.z * scale * w4.z) | ((unsigned int)f2bu(v.w * scale * w4.w) << 16);
    *(uint2*)(out + (size_t)row * DIM + tx * 4) = o;
}

// ---------------- weight transpose + cast: in (K x Nc) f32 -> out (Nc x K) bf16 ----------------
__global__ void transpose_cast_kernel(const float* __restrict__ in, bf16* __restrict__ out,
                                      int K, int Nc) {
    __shared__ float tile[32][33];
    int n0 = blockIdx.x * 32, k0 = blockIdx.y * 32;
    int tx = threadIdx.x & 31, ty = threadIdx.x >> 5;
#pragma unroll
    for (int i = 0; i < 32; i += 8)
        tile[ty + i][tx] = in[(size_t)(k0 + ty + i) * Nc + n0 + tx];
    __syncthreads();
#pragma unroll
    for (int i = 0; i < 32; i += 8)
        out[(size_t)(n0 + ty + i) * K + k0 + tx] = __float2bfloat16(tile[tx][ty + i]);
}

// ---------------- per-layer params ----------------
__global__ void prep_kernel(const float* __restrict__ dlog, const float* __restrict__ alog,
                            const float* __restrict__ glog, const float* __restrict__ kern,
                            float* __restrict__ prm) {
    int l = blockIdx.x, t = threadIdx.x;
    float* p = prm + l * PRMS;
    if (t < RNK) {
        float g = 0.85f + 0.15f * sigm(dlog[l * RNK + t]);
        float lg = logf(g);
        p[t] = g;
        p[16 + t] = lg;
        p[32 + t] = expf(lg * (float)CHK);
        p[48 + t] = sigm(alog[l * RNK + t]);   // ACAP = 1.0
    }
    if (t < KT) {
        float gate = sigm(glog[l]);
        p[64 + t] = gate * kern[l * KT + t];
    }
}

// ---------------- pack u,v (D x R each) -> uvT (32 x D) bf16 per layer ----------------
__global__ void prep_uv_kernel(const float* __restrict__ u, const float* __restrict__ v,
                               bf16* __restrict__ uvT) {
    int l = blockIdx.y;
    int k = blockIdx.x * 256 + threadIdx.x;
    const float* ul = u + (size_t)l * DIM * RNK;
    const float* vl = v + (size_t)l * DIM * RNK;
    bf16* o = uvT + (size_t)l * 32 * DIM;
#pragma unroll
    for (int r = 0; r < RNK; ++r) {
        o[(size_t)r * DIM + k] = __float2bfloat16(ul[(size_t)k * RNK + r]);
        o[(size_t)(RNK + r) * DIM + k] = __float2bfloat16(vl[(size_t)k * RNK + r]);
    }
}

// ---------------- gated causal conv: Zc = bf16( gate * conv(hn) ) ----------------
__global__ void conv_kernel(const bf16* __restrict__ hn, const float* __restrict__ prm,
                            bf16* __restrict__ Zc) {
    int t = blockIdx.x * 256 + threadIdx.x;
    int d4 = (t & 255) * 4;
    int row = t >> 8;
    int n = row & (SEQ - 1);
    float a0 = 0, a1 = 0, a2 = 0, a3 = 0;
#pragma unroll
    for (int kk = 0; kk < KT; ++kk) {
        if (n - kk < 0) break;
        float wv = prm[64 + kk];
        uint2 hv = *(const uint2*)(hn + (size_t)(row - kk) * DIM + d4);
        a0 += wv * bfu(hv.x & 0xffffu);
        a1 += wv * bfu(hv.x >> 16);
        a2 += wv * bfu(hv.y & 0xffffu);
        a3 += wv * bfu(hv.y >> 16);
    }
    uint2 o;
    o.x = f2bu(a0) | ((unsigned int)f2bu(a1) << 16);
    o.y = f2bu(a2) | ((unsigned int)f2bu(a3) << 16);
    *(uint2*)(Zc + (size_t)row * DIM + d4) = o;
}

// ---------------- q/k projection + l2norm via MFMA (16 rows / 1-wave block) ----------------
__global__ __launch_bounds__(64)
void qk_mfma_kernel(const bf16* __restrict__ hn, const bf16* __restrict__ uvT,
                    const float* __restrict__ prm, float* __restrict__ qa,
                    float* __restrict__ kn) {
    int row0 = blockIdx.x * 16;
    int lane = threadIdx.x;
    int fr = lane & 15, kf = (lane >> 4) * 8;
    vf4 accq = {}, acck = {};
#pragma unroll 4
    for (int kt = 0; kt < DIM / 32; ++kt) {
        int k0 = kt * 32;
        bh8 b0 = *(const bh8*)(uvT + (size_t)fr * DIM + k0 + kf);
        bh8 b1 = *(const bh8*)(uvT + (size_t)(16 + fr) * DIM + k0 + kf);
        bh8 a0 = *(const bh8*)(hn + (size_t)(row0 + fr) * DIM + k0 + kf);
        accq = __builtin_amdgcn_mfma_f32_16x16x32_bf16(a0, b0, accq, 0, 0, 0);
        acck = __builtin_amdgcn_mfma_f32_16x16x32_bf16(a0, b1, acck, 0, 0, 0);
    }
    int fq = lane >> 4;
    float alpha = prm[48 + fr];
#pragma unroll
    for (int j = 0; j < 4; ++j) {
        float qv = accq[j], kv = acck[j];
        float sq = qv * qv, sk = kv * kv;
#pragma unroll
        for (int mask = 1; mask < 16; mask <<= 1) {
            sq += __shfl_xor(sq, mask);
            sk += __shfl_xor(sk, mask);
        }
        int row = row0 + fq * 4 + j;
        qa[(size_t)row * RNK + fr] = qv / fmaxf(sqrtf(sq), 1e-8f) * alpha;
        kn[(size_t)row * RNK + fr] = kv / fmaxf(sqrtf(sk), 1e-8f);
    }
}

// ---------------- per-chunk transpose of hn into HB[bc][d][0..128) ----------------
__global__ void trans_hn_kernel(const bf16* __restrict__ hn, bf16* __restrict__ HB) {
    __shared__ bf16 tile[32][40];
    int bc = blockIdx.x;
    int d0 = blockIdx.y * 32, j0 = blockIdx.z * 32;
    int tx = threadIdx.x & 31, ty = threadIdx.x >> 5;
    size_t rowb = (size_t)bc * CHK;
#pragma unroll
    for (int i = 0; i < 32; i += 8)
        tile[ty + i][tx] = hn[(rowb + j0 + ty + i) * DIM + d0 + tx];
    __syncthreads();
    bf16* Hp = HB + (size_t)bc * DIM * KAPP;
#pragma unroll
    for (int i = 0; i < 32; i += 8)
        Hp[(size_t)(d0 + ty + i) * KAPP + j0 + tx] = tile[tx][ty + i];
}

// ---------------- scores + apply-A assembly + kdt (split over i-tiles) ----------------
__global__ void scores_kernel(const float* __restrict__ qa, const float* __restrict__ kn,
                              const float* __restrict__ prm, bf16* __restrict__ SA,
                              bf16* __restrict__ kdtB) {
    int bc = blockIdx.x;
    int yt = blockIdx.y;
    __shared__ float ptab[CHK][16];
    for (int e = threadIdx.x; e < CHK * 16; e += 256) {
        int tt = e >> 4, r = e & 15;
        ptab[tt][r] = expf(prm[16 + r] * (float)tt);
    }
    __syncthreads();
    size_t rowb = (size_t)bc * CHK;
    bf16* SAp = SA + (size_t)bc * CHK * KAPP;
    for (int e = threadIdx.x; e < 16 * CHK; e += 256) {
        int i = yt * 16 + (e >> 7), j = e & (CHK - 1);
        float vsum = 0.f;
        if (i >= j) {
            const float* qp = qa + (rowb + i) * RNK;
            const float* kp = kn + (rowb + j) * RNK;
#pragma unroll
            for (int r = 0; r < 16; ++r) vsum += qp[r] * ptab[i - j][r] * kp[r];
        }
        SAp[(size_t)i * KAPP + j] = __float2bfloat16(vsum);
    }
    for (int e = threadIdx.x; e < 16 * 32; e += 256) {
        int i = yt * 16 + (e >> 5), rr = e & 31;
        float w = 0.f;
        if (rr < 16) w = qa[(rowb + i) * RNK + rr] * expf(prm[16 + rr] * (float)(i + 1));
        SAp[(size_t)i * KAPP + CHK + rr] = __float2bfloat16(w);
    }
    bf16* kp2 = kdtB + (size_t)bc * RNK * CHK;
    for (int e = threadIdx.x; e < 2 * CHK; e += 256) {
        int r = 2 * yt + (e >> 7), j = e & (CHK - 1);
        kp2[(size_t)r * CHK + j] =
            __float2bfloat16(ptab[CHK - 1 - j][r] * kn[(rowb + j) * RNK + r]);
    }
}

// ---------------- chunkU via MFMA ----------------
__global__ __launch_bounds__(64)
void chunkU_kernel(const bf16* __restrict__ HB, const bf16* __restrict__ kdtB,
                   float* __restrict__ U) {
    int bc = blockIdx.x;
    int d0 = blockIdx.y * 64;
    int lane = threadIdx.x;
    int fr = lane & 15, kf = (lane >> 4) * 8;
    const bf16* Hp = HB + (size_t)bc * DIM * KAPP;
    const bf16* Kp = kdtB + (size_t)bc * RNK * CHK;
    vf4 acc[4] = {};
#pragma unroll
    for (int kt = 0; kt < 4; ++kt) {
        int k0 = kt * 32;
        bh8 bb = *(const bh8*)(Kp + (size_t)fr * CHK + k0 + kf);
#pragma unroll
        for (int m = 0; m < 4; ++m) {
            bh8 a = *(const bh8*)(Hp + (size_t)(d0 + m * 16 + fr) * KAPP + k0 + kf);
            acc[m] = __builtin_amdgcn_mfma_f32_16x16x32_bf16(a, bb, acc[m], 0, 0, 0);
        }
    }
    int fq = lane >> 4;
    float* Up = U + (size_t)bc * DIM * RNK;
#pragma unroll
    for (int m = 0; m < 4; ++m)
#pragma unroll
        for (int j = 0; j < 4; ++j)
            Up[(size_t)(d0 + m * 16 + fq * 4 + j) * RNK + fr] = acc[m][j];
}

// ---------------- chunk scan: P^T bf16 into HB[bc][d][128..144), 4 ranks/thread ----------------
__global__ void scanP_kernel(const float* __restrict__ U, const float* __restrict__ prm,
                             bf16* __restrict__ HB) {
    int g = blockIdx.x * 256 + threadIdx.x;
    int rq = g & 3;
    int d = (g >> 2) & (DIM - 1);
    int b = g >> 12;
    float gC[4], p[4];
#pragma unroll
    for (int q = 0; q < 4; ++q) { gC[q] = prm[32 + rq * 4 + q]; p[q] = 0.f; }
    for (int c = 0; c < NCH; ++c) {
        int bc = b * NCH + c;
        uint2 pk;
        pk.x = (unsigned int)f2bu(p[0]) | ((unsigned int)f2bu(p[1]) << 16);
        pk.y = (unsigned int)f2bu(p[2]) | ((unsigned int)f2bu(p[3]) << 16);
        *(uint2*)(HB + (size_t)bc * DIM * KAPP + (size_t)d * KAPP + CHK + rq * 4) = pk;
        float4 u4 = *(const float4*)(U + ((size_t)bc * DIM + d) * RNK + rq * 4);
        p[0] = gC[0] * p[0] + u4.x;
        p[1] = gC[1] * p[1] + u4.y;
        p[2] = gC[2] * p[2] + u4.z;
        p[3] = gC[3] * p[3] + u4.w;
    }
}

// ---------------- apply GEMM: Zb = bf16( Zc + SA[bc] @ HB[bc]^T ) ----------------
__global__ __launch_bounds__(256)
void apply_gemm_kernel(const bf16* __restrict__ SA, const bf16* __restrict__ HB,
                       const bf16* __restrict__ Zc, bf16* __restrict__ Zb) {
    __shared__ alignas(16) bf16 As[128][40];
    __shared__ alignas(16) bf16 Bs[128][40];
    int bc = blockIdx.y;
    int colB0 = blockIdx.x * 128;
    int t = threadIdx.x;
    int lane = t & 63, wid = t >> 6;
    int wr = wid >> 1, wc = wid & 1;
    vf4 acc[4][4] = {};
    const bf16* A = SA + (size_t)bc * CHK * KAPP;
    const bf16* BT = HB + (size_t)bc * DIM * KAPP;
    int r1 = t >> 2, ko1 = (t & 3) * 8;
    int fr = lane & 15, kf = (lane >> 4) * 8;
#pragma unroll
    for (int kt = 0; kt < 5; ++kt) {
        int k0 = kt * 32;
        int4 va1 = *(const int4*)(A + (size_t)r1 * KAPP + k0 + ko1);
        int4 va2 = *(const int4*)(A + (size_t)(r1 + 64) * KAPP + k0 + ko1);
        int4 vb1 = *(const int4*)(BT + (size_t)(colB0 + r1) * KAPP + k0 + ko1);
        int4 vb2 = *(const int4*)(BT + (size_t)(colB0 + r1 + 64) * KAPP + k0 + ko1);
        __syncthreads();
        *(int4*)&As[r1][ko1] = va1;
        *(int4*)&As[r1 + 64][ko1] = va2;
        *(int4*)&Bs[r1][ko1] = vb1;
        *(int4*)&Bs[r1 + 64][ko1] = vb2;
        __syncthreads();
        bh8 a[4], bb[4];
#pragma unroll
        for (int m = 0; m < 4; ++m) a[m] = *(const bh8*)&As[wr * 64 + m * 16 + fr][kf];
#pragma unroll
        for (int n = 0; n < 4; ++n) bb[n] = *(const bh8*)&Bs[wc * 64 + n * 16 + fr][kf];
#pragma unroll
        for (int m = 0; m < 4; ++m)
#pragma unroll
            for (int n = 0; n < 4; ++n)
                acc[m][n] = __builtin_amdgcn_mfma_f32_16x16x32_bf16(a[m], bb[n], acc[m][n], 0, 0, 0);
    }
    int fq = lane >> 4;
    size_t rowb = (size_t)bc * CHK;
#pragma unroll
    for (int m = 0; m < 4; ++m) {
#pragma unroll
        for (int n = 0; n < 4; ++n) {
            int col = colB0 + wc * 64 + n * 16 + fr;
#pragma unroll
            for (int j = 0; j < 4; ++j) {
                size_t row = rowb + wr * 64 + m * 16 + fq * 4 + j;
                size_t idx = row * DIM + col;
                Zb[idx] = __float2bfloat16(b2f(Zc[idx]) + acc[m][n][j]);
            }
        }
    }
}

// ---------------- 128-tile m97-structure GEMM (lda-parameterized) ----------------
// EPI 1: out = res + acc + bias (f32, in-place)
template <int EPI>
__global__ __launch_bounds__(256)
void gemm_kernel(const bf16* __restrict__ A, const bf16* __restrict__ BT,
                 const float* __restrict__ bias, const float* __restrict__ res,
                 float* __restrict__ outF, bf16* __restrict__ outB,
                 int M, int Nc, int K, int lda) {
    __shared__ alignas(16) bf16 As[128][32];
    __shared__ alignas(16) bf16 Bs[128][32];
    int gx = gridDim.x;
    int orig = blockIdx.y * gx + blockIdx.x;
    int qch = (gx * gridDim.y) >> 3;
    int wg = (orig & 7) * qch + (orig >> 3);
    int bn = wg % gx, bm = wg / gx;
    int t = threadIdx.x;
    int lane = t & 63, wid = t >> 6;
    int wr = wid >> 1, wc = wid & 1;
    vf4 acc[4][4] = {};
    const int rowA0 = bm * 128, colB0 = bn * 128;
    int fr = lane & 15, kf = (lane >> 4) * 8;
    int c0 = wid * 2;
    int lrow = lane >> 2;
    int lcol = (lane & 3) * 8;
    const bf16* Ag0 = A + (size_t)(rowA0 + c0 * 16 + lrow) * lda + lcol;
    const bf16* Ag1 = A + (size_t)(rowA0 + c0 * 16 + 16 + lrow) * lda + lcol;
    const bf16* Bg0 = BT + (size_t)(colB0 + c0 * 16 + lrow) * lda + lcol;
    const bf16* Bg1 = BT + (size_t)(colB0 + c0 * 16 + 16 + lrow) * lda + lcol;
    bf16* Al0 = &As[0][0] + c0 * 512;
    bf16* Al1 = Al0 + 512;
    bf16* Bl0 = &Bs[0][0] + c0 * 512;
    bf16* Bl1 = Bl0 + 512;
    int nk = K >> 5;
    for (int kt = 0; kt < nk; ++kt) {
        int k0 = kt * 32;
        __syncthreads();
        gld16(Ag0 + k0, Al0);
        gld16(Ag1 + k0, Al1);
        gld16(Bg0 + k0, Bl0);
        gld16(Bg1 + k0, Bl1);
        asm volatile("s_waitcnt vmcnt(0)" ::: "memory");
        __syncthreads();
        bh8 a[4], bb[4];
#pragma unroll
        for (int m = 0; m < 4; ++m) a[m] = *(const bh8*)&As[wr * 64 + m * 16 + fr][kf];
#pragma unroll
        for (int n = 0; n < 4; ++n) bb[n] = *(const bh8*)&Bs[wc * 64 + n * 16 + fr][kf];
#pragma unroll
        for (int m = 0; m < 4; ++m)
#pragma unroll
            for (int n = 0; n < 4; ++n)
                acc[m][n] = __builtin_amdgcn_mfma_f32_16x16x32_bf16(a[m], bb[n], acc[m][n], 0, 0, 0);
    }
    int fq = lane >> 4;
#pragma unroll
    for (int m = 0; m < 4; ++m) {
#pragma unroll
        for (int n = 0; n < 4; ++n) {
            int col = colB0 + wc * 64 + n * 16 + fr;
            float bv = bias[col];
#pragma unroll
            for (int j = 0; j < 4; ++j) {
                int row = rowA0 + wr * 64 + m * 16 + fq * 4 + j;
                size_t idx = (size_t)row * Nc + col;
                float v2 = acc[m][n][j] + bv;
                if (EPI == 1) v2 += res[idx];
                outF[idx] = v2;
            }
        }
    }
}

// ---------------- 256-tile 2-phase GEMM (r10 schedule; EPI0 adds LDS-transposed NT epilogue) ----------------
// NOTE r11 lesson: acc[8][4]=128 VGPR/lane caps this tile at 2 waves/SIMD — do NOT set
// min-waves=4 (forces 128-reg cap -> accumulator spill -> 11 GB scratch traffic, 4x slower).
// EPI 0: f32 out+bias via per-wave LDS transpose + FULL-128B-LINE nontemporal stores
//        (r9 NT fail was 64B partial lines; full lines keep A/B L3-resident without
//        write amplification). EPI 2: bf16 gelu(out+bias); EPI 4: bf16 split-K partial
#define SB __builtin_amdgcn_sched_barrier(0)
template <int EPI>
__global__ __launch_bounds__(512, 2)
void gemm256_kernel(const bf16* __restrict__ A, const bf16* __restrict__ BT,
                    const float* __restrict__ bias,
                    float* __restrict__ outF, bf16* __restrict__ outB,
                    int M, int Nc, int K, int lda) {
    extern __shared__ char smem[];
    bf16* Alds = (bf16*)smem;             // 2dbuf x 2kh x 8192 elems
    bf16* Blds = (bf16*)(smem + 65536);
    if (EPI == 4) {
        size_t zo = (size_t)blockIdx.z * K;
        A += zo; BT += zo;
        outB += (size_t)blockIdx.z * ((size_t)M * Nc);
    }
    int gx = gridDim.x, gy = gridDim.y;
    int orig = blockIdx.y * gx + blockIdx.x;
    int qch = (gx * gy) >> 3;
    int wg = (orig & 7) * qch + (orig >> 3);
    int bm = wg % gy, bn = wg / gy;   // column-major: XCD chunk shares bn panels
    int rowA0 = bm * 256, colB0 = bn * 256;
    int tid = threadIdx.x;
    int lane = tid & 63, wid = tid >> 6;
    int wm = wid >> 2, wn = wid & 3;
    int fr = lane & 15;
    int kf8 = ((((lane >> 4) & 3) ^ ((fr >> 1) & 3)) * 8);
    int srow = wid * 16 + (lane >> 2);
    int scol = (((lane & 3) ^ ((lane >> 3) & 3)) * 8);
    const bf16* Ags = A + (size_t)(rowA0 + srow) * lda + scol;
    const bf16* Bgs = BT + (size_t)(colB0 + srow) * lda + scol;
    int sbase = wid * 512;
    auto stA = [&](int d, int kh, int k0) {
        bf16* dst = Alds + (d * 2 + kh) * 8192 + sbase;
        const bf16* src = Ags + k0 + kh * 32;
        gld16(src, dst);
        gld16(src + (size_t)128 * lda, dst + 4096);
    };
    auto stB = [&](int d, int kh, int k0) {
        bf16* dst = Blds + (d * 2 + kh) * 8192 + sbase;
        const bf16* src = Bgs + k0 + kh * 32;
        gld16(src, dst);
        gld16(src + (size_t)128 * lda, dst + 4096);
    };
    const bf16* Ard = Alds + (size_t)(wm * 128 + fr) * 32 + kf8;
    const bf16* Brd = Blds + (size_t)(wn * 64 + fr) * 32 + kf8;
    vf4 acc[8][4] = {};
    int ntk = K >> 6;
    // prologue: B then A of tile 0 -> queue [B0 x4, A0 x4]
    stB(0, 0, 0); stB(0, 1, 0); stA(0, 0, 0); stA(0, 1, 0);
    for (int t = 0; t < ntk; ++t) {
        int d = t & 1, nd = d ^ 1;
        int k1 = (t + 1) << 6;
        bool pf = (t + 1 < ntk);
        int dof = d * 16384;          // kh0 of dbuf d
        int dof1 = dof + 8192;        // kh1
        bh8 bF0[4], bF1[4];
        // ---- P0: stage B(nd), wait buf d, read A m0-3 + B (kk0,kk1), MFMA acc[0..3] ----
        if (pf) { stB(nd, 0, k1); stB(nd, 1, k1);
                  asm volatile("s_waitcnt vmcnt(4)" ::: "memory"); }
        else    { asm volatile("s_waitcnt vmcnt(0)" ::: "memory"); }
        SB; __builtin_amdgcn_s_barrier(); SB;
        {
            bh8 a00 = *(const bh8*)(Ard + dof + 0 * 512);
            bh8 a01 = *(const bh8*)(Ard + dof + 1 * 512);
            bh8 a02 = *(const bh8*)(Ard + dof + 2 * 512);
            bh8 a03 = *(const bh8*)(Ard + dof + 3 * 512);
            bh8 a10 = *(const bh8*)(Ard + dof1 + 0 * 512);
            bh8 a11 = *(const bh8*)(Ard + dof1 + 1 * 512);
            bh8 a12 = *(const bh8*)(Ard + dof1 + 2 * 512);
            bh8 a13 = *(const bh8*)(Ard + dof1 + 3 * 512);
#pragma unroll
            for (int n = 0; n < 4; ++n) {
                bF0[n] = *(const bh8*)(Brd + dof + n * 512);
                bF1[n] = *(const bh8*)(Brd + dof1 + n * 512);
            }
            __builtin_amdgcn_s_setprio(1);
#pragma unroll
            for (int n = 0; n < 4; ++n) {
                acc[0][n] = __builtin_amdgcn_mfma_f32_16x16x32_bf16(a00, bF0[n], acc[0][n], 0, 0, 0);
                acc[1][n] = __builtin_amdgcn_mfma_f32_16x16x32_bf16(a01, bF0[n], acc[1][n], 0, 0, 0);
                acc[2][n] = __builtin_amdgcn_mfma_f32_16x16x32_bf16(a02, bF0[n], acc[2][n], 0, 0, 0);
                acc[3][n] = __builtin_amdgcn_mfma_f32_16x16x32_bf16(a03, bF0[n], acc[3][n], 0, 0, 0);
            }
#pragma unroll
            for (int n = 0; n < 4; ++n) {
                acc[0][n] = __builtin_amdgcn_mfma_f32_16x16x32_bf16(a10, bF1[n], acc[0][n], 0, 0, 0);
                acc[1][n] = __builtin_amdgcn_mfma_f32_16x16x32_bf16(a11, bF1[n], acc[1][n], 0, 0, 0);
                acc[2][n] = __builtin_amdgcn_mfma_f32_16x16x32_bf16(a12, bF1[n], acc[2][n], 0, 0, 0);
                acc[3][n] = __builtin_amdgcn_mfma_f32_16x16x32_bf16(a13, bF1[n], acc[3][n], 0, 0, 0);
            }
            __builtin_amdgcn_s_setprio(0);
        }
        SB;
        // ---- P1: stage A(nd), barrier, read A m4-7 (kk0,kk1), MFMA acc[4..7] ----
        if (pf) { stA(nd, 0, k1); stA(nd, 1, k1); }
        SB; __builtin_amdgcn_s_barrier(); SB;
        {
            bh8 a00 = *(const bh8*)(Ard + dof + 4 * 512);
            bh8 a01 = *(const bh8*)(Ard + dof + 5 * 512);
            bh8 a02 = *(const bh8*)(Ard + dof + 6 * 512);
            bh8 a03 = *(const bh8*)(Ard + dof + 7 * 512);
            bh8 a10 = *(const bh8*)(Ard + dof1 + 4 * 512);
            bh8 a11 = *(const bh8*)(Ard + dof1 + 5 * 512);
            bh8 a12 = *(const bh8*)(Ard + dof1 + 6 * 512);
            bh8 a13 = *(const bh8*)(Ard + dof1 + 7 * 512);
            __builtin_amdgcn_s_setprio(1);
#pragma unroll
            for (int n = 0; n < 4; ++n) {
                acc[4][n] = __builtin_amdgcn_mfma_f32_16x16x32_bf16(a00, bF0[n], acc[4][n], 0, 0, 0);
                acc[5][n] = __builtin_amdgcn_mfma_f32_16x16x32_bf16(a01, bF0[n], acc[5][n], 0, 0, 0);
                acc[6][n] = __builtin_amdgcn_mfma_f32_16x16x32_bf16(a02, bF0[n], acc[6][n], 0, 0, 0);
                acc[7][n] = __builtin_amdgcn_mfma_f32_16x16x32_bf16(a03, bF0[n], acc[7][n], 0, 0, 0);
            }
#pragma unroll
            for (int n = 0; n < 4; ++n) {
                acc[4][n] = __builtin_amdgcn_mfma_f32_16x16x32_bf16(a10, bF1[n], acc[4][n], 0, 0, 0);
                acc[5][n] = __builtin_amdgcn_mfma_f32_16x16x32_bf16(a11, bF1[n], acc[5][n], 0, 0, 0);
                acc[6][n] = __builtin_amdgcn_mfma_f32_16x16x32_bf16(a12, bF1[n], acc[6][n], 0, 0, 0);
                acc[7][n] = __builtin_amdgcn_mfma_f32_16x16x32_bf16(a13, bF1[n], acc[7][n], 0, 0, 0);
            }
            __builtin_amdgcn_s_setprio(0);
        }
        SB;
    }
    int fq = lane >> 4;
    if (EPI == 0) {
        // LDS-transposed full-line NT epilogue: per-wave 4KB region, per 16x64 frag:
        // scatter acc -> LDS, read back 8 lanes x 16B = full 128B line, NT-store.
        __syncthreads();   // all waves done reading main-loop LDS
        float* W = (float*)smem + wid * 1024;   // 16 rows x 64 cols f32 = 4KB/wave
        int rr = lane >> 3;           // 0..7
        int cb = (lane & 7) * 4;      // f32 col offset 0,4,..28
#pragma unroll
        for (int mi = 0; mi < 8; ++mi) {
#pragma unroll
            for (int ni = 0; ni < 4; ++ni)
#pragma unroll
                for (int j = 0; j < 4; ++j)
                    W[(fq * 4 + j) * 64 + ni * 16 + fr] = acc[mi][ni][j];
            // compiler orders ds_read-after-ds_write via lgkmcnt (same LDS alias)
#pragma unroll
            for (int p = 0; p < 2; ++p) {
#pragma unroll
                for (int q = 0; q < 2; ++q) {
                    vf4 v = *(vf4*)&W[(p * 8 + rr) * 64 + q * 32 + cb];
                    int col = colB0 + wn * 64 + q * 32 + cb;
                    int row = rowA0 + wm * 128 + mi * 16 + p * 8 + rr;
                    vf4 bv4 = *(const vf4*)&bias[col];
                    v += bv4;
                    __builtin_nontemporal_store(v, (vf4*)&outF[(size_t)row * Nc + col]);
                }
            }
            __syncthreads();   // wave-region reuse is per-wave, but keep iterations aligned cheaply
        }
    } else {
#pragma unroll
        for (int mi = 0; mi < 8; ++mi) {
#pragma unroll
            for (int ni = 0; ni < 4; ++ni) {
                int col = colB0 + wn * 64 + ni * 16 + fr;
                float bv = (EPI == 4) ? 0.f : bias[col];
#pragma unroll
                for (int j = 0; j < 4; ++j) {
                    int row = rowA0 + wm * 128 + mi * 16 + fq * 4 + j;
                    size_t idx = (size_t)row * Nc + col;
                    float v2 = acc[mi][ni][j] + bv;
                    if (EPI == 2) outB[idx] = __float2bfloat16(gelu_t(v2));
                    else outB[idx] = __float2bfloat16(v2);
                }
            }
        }
    }
}

// ---------------- fused split-K combine (bf16 partials) + rmsnorm ----------------
__global__ void combine4_norm_kernel(const bf16* __restrict__ P, const float* __restrict__ bias,
                                     const float* __restrict__ nw, float* __restrict__ h,
                                     bf16* __restrict__ hnb) {
    int row = blockIdx.x;
    int tx = threadIdx.x;
    const size_t S = (size_t)BNROWS * DIM;
    size_t base = (size_t)row * DIM + tx * 4;
    float4 hv = *(float4*)(h + base);
    float4 bv = ((const float4*)bias)[tx];
    float s0 = bv.x, s1 = bv.y, s2 = bv.z, s3 = bv.w;
#pragma unroll
    for (int q = 0; q < 4; ++q) {
        uint2 pk = *(const uint2*)(P + q * S + base);
        s0 += bfu(pk.x & 0xffffu);
        s1 += bfu(pk.x >> 16);
        s2 += bfu(pk.y & 0xffffu);
        s3 += bfu(pk.y >> 16);
    }
    hv.x += s0; hv.y += s1; hv.z += s2; hv.w += s3;
    *(float4*)(h + base) = hv;
    float ss = hv.x * hv.x + hv.y * hv.y + hv.z * hv.z + hv.w * hv.w;
#pragma unroll
    for (int off = 32; off > 0; off >>= 1) ss += __shfl_down(ss, off);
    __shared__ float red[4];
    int lane = tx & 63, wv = tx >> 6;
    if (lane == 0) red[wv] = ss;
    __syncthreads();
    float tot = red[0] + red[1] + red[2] + red[3];
    float scale = rsqrtf(tot * (1.f / DIM) + 1e-6f);
    float4 w4 = ((const float4*)nw)[tx];
    uint2 o;
    o.x = f2bu(hv.x * scale * w4.x) | ((unsigned int)f2bu(hv.y * scale * w4.y) << 16);
    o.y = f2bu(hv.z * scale * w4.z) | ((unsigned int)f2bu(hv.w * scale * w4.w) << 16);
    *(uint2*)(hnb + (size_t)row * DIM + tx * 4) = o;
}

// ===================================================================
extern "C" void kernel_launch(void* const* d_in, const int* in_sizes, int n_in,
                              void* d_out, int out_size, void* d_ws, size_t ws_size,
                              hipStream_t stream) {
    (void)in_sizes; (void)n_in; (void)out_size; (void)ws_size;
    const int* tokens = (const int*)d_in[0];
    const float* emb = (const float*)d_in[1];
    const float* k1a_nw = (const float*)d_in[2];
    const float* k1a_w1 = (const float*)d_in[3];
    const float* k1a_b1 = (const float*)d_in[4];
    const float* k1a_w2 = (const float*)d_in[5];
    const float* k1a_b2 = (const float*)d_in[6];
    const float* k2_u = (const float*)d_in[7];
    const float* k2_v = (const float*)d_in[8];
    const float* k2_dlog = (const float*)d_in[9];
    const float* k2_alog = (const float*)d_in[10];
    const float* k2_glog = (const float*)d_in[11];
    const float* k2_kern = (const float*)d_in[12];
    const float* k2_pw = (const float*)d_in[13];
    const float* k2_pb = (const float*)d_in[14];
    const float* k2_n1w = (const float*)d_in[15];
    const float* k2_n2w = (const float*)d_in[16];
    const float* k2_w1 = (const float*)d_in[17];
    const float* k2_b1 = (const float*)d_in[18];
    const float* k2_w2 = (const float*)d_in[19];
    const float* k2_b2 = (const float*)d_in[20];
    const float* k1b_nw = (const float*)d_in[21];
    const float* k1b_w1 = (const float*)d_in[22];
    const float* k1b_b1 = (const float*)d_in[23];
    const float* k1b_w2 = (const float*)d_in[24];
    const float* k1b_b2 = (const float*)d_in[25];
    const float* k0_nw = (const float*)d_in[26];
    const float* head_w = (const float*)d_in[27];
    const float* head_b = (const float*)d_in[28];
    float* out = (float*)d_out;

    (void)hipFuncSetAttribute((const void*)gemm256_kernel<0>,
                              hipFuncAttributeMaxDynamicSharedMemorySize, 131072);
    (void)hipFuncSetAttribute((const void*)gemm256_kernel<2>,
                              hipFuncAttributeMaxDynamicSharedMemorySize, 131072);
    (void)hipFuncSetAttribute((const void*)gemm256_kernel<4>,
                              hipFuncAttributeMaxDynamicSharedMemorySize, 131072);

    // ---- workspace carve ----
    char* wsp = (char*)d_ws;
    auto alloc = [&](size_t bytes) -> char* {
        char* p = wsp;
        wsp += (bytes + 255) & ~(size_t)255;
        return p;
    };
    float* h   = (float*)alloc((size_t)BNROWS * DIM * 4);
    bf16* Zc   = (bf16*)alloc((size_t)BNROWS * DIM * 2);
    bf16* hnb  = (bf16*)alloc((size_t)BNROWS * DIM * 2);
    bf16* Zb   = (bf16*)alloc((size_t)BNROWS * DIM * 2);
    bf16* t1b  = (bf16*)alloc((size_t)BNROWS * HID * 2);
    float* qaB = (float*)alloc((size_t)BNROWS * RNK * 4);
    float* knB = (float*)alloc((size_t)BNROWS * RNK * 4);
    float* U   = (float*)alloc((size_t)BATCH * NCH * DIM * RNK * 4);
    bf16* HB   = (bf16*)alloc((size_t)BATCH * NCH * DIM * KAPP * 2);
    bf16* SA   = (bf16*)alloc((size_t)BATCH * NCH * CHK * KAPP * 2);
    bf16* kdtB = (bf16*)alloc((size_t)BATCH * NCH * RNK * CHK * 2);
    float* prm = (float*)alloc((size_t)NL * PRMS * 4);
    bf16* uvT  = (bf16*)alloc((size_t)NL * 32 * DIM * 2);
    bf16* w1aT = (bf16*)alloc((size_t)HID * DIM * 2);
    bf16* w2aT = (bf16*)alloc((size_t)DIM * HID * 2);
    bf16* w1bT = (bf16*)alloc((size_t)HID * DIM * 2);
    bf16* w2bT = (bf16*)alloc((size_t)DIM * HID * 2);
    bf16* pwT  = (bf16*)alloc((size_t)NL * DIM * DIM * 2);
    bf16* w1T  = (bf16*)alloc((size_t)NL * DIM * HID * 2);
    bf16* w2T  = (bf16*)alloc((size_t)NL * HID * DIM * 2);
    bf16* headT = (bf16*)alloc((size_t)VOC * DIM * 2);
    bf16* Pk  = (bf16*)alloc((size_t)4 * BNROWS * DIM * 2);   // split-K partials (bf16)

    hipMemsetAsync(HB, 0, (size_t)BATCH * NCH * DIM * KAPP * 2, stream);

    auto T = [&](const float* in, bf16* o, int K, int Nc) {
        transpose_cast_kernel<<<dim3(Nc / 32, K / 32), 256, 0, stream>>>(in, o, K, Nc);
    };
    // ---- weight prep ----
    T(k1a_w1, w1aT, DIM, HID);
    T(k1a_w2, w2aT, HID, DIM);
    T(k1b_w1, w1bT, DIM, HID);
    T(k1b_w2, w2bT, HID, DIM);
    for (int l = 0; l < NL; ++l) {
        T(k2_pw + (size_t)l * DIM * DIM, pwT + (size_t)l * DIM * DIM, DIM, DIM);
        T(k2_w1 + (size_t)l * DIM * HID, w1T + (size_t)l * DIM * HID, DIM, HID);
        T(k2_w2 + (size_t)l * HID * DIM, w2T + (size_t)l * HID * DIM, HID, DIM);
    }
    T(head_w, headT, DIM, VOC);
    prep_kernel<<<NL, 32, 0, stream>>>(k2_dlog, k2_alog, k2_glog, k2_kern, prm);
    prep_uv_kernel<<<dim3(DIM / 256, NL), 256, 0, stream>>>(k2_u, k2_v, uvT);

    // mlp core: assumes hnb holds rmsnorm of h; leaves h updated and hnb = rmsnorm(h, nw_next)
    auto mlp_core = [&](const bf16* W1, const float* B1, const bf16* W2, const float* B2,
                        const float* nw_next) {
        gemm256_kernel<2><<<dim3(HID / 256, BNROWS / 256), 512, 131072, stream>>>(
            hnb, W1, B1, nullptr, t1b, BNROWS, HID, DIM, DIM);
        gemm256_kernel<4><<<dim3(DIM / 256, BNROWS / 256, 4), 512, 131072, stream>>>(
            t1b, W2, nullptr, nullptr, Pk, BNROWS, DIM, HID / 4, HID);
        combine4_norm_kernel<<<BNROWS, 256, 0, stream>>>(Pk, B2, nw_next, h, hnb);
    };

    // ---- forward ----
    embed_kernel<<<BNROWS, 256, 0, stream>>>(tokens, emb, h);
    rmsnorm_kernel<<<BNROWS, 256, 0, stream>>>(h, k1a_nw, hnb);
    mlp_core(w1aT, k1a_b1, w2aT, k1a_b2, k2_n1w);   // -> hnb = rmsnorm(h, n1w[0])

    for (int l = 0; l < NL; ++l) {
        const float* prm_l = prm + l * PRMS;
        conv_kernel<<<BNROWS, 256, 0, stream>>>(hnb, prm_l, Zc);
        qk_mfma_kernel<<<BNROWS / 16, 64, 0, stream>>>(hnb, uvT + (size_t)l * 32 * DIM,
                                                       prm_l, qaB, knB);
        trans_hn_kernel<<<dim3(BATCH * NCH, DIM / 32, CHK / 32), 256, 0, stream>>>(hnb, HB);
        scores_kernel<<<dim3(BATCH * NCH, 8), 256, 0, stream>>>(qaB, knB, prm_l, SA, kdtB);
        chunkU_kernel<<<dim3(BATCH * NCH, DIM / 64), 64, 0, stream>>>(HB, kdtB, U);
        scanP_kernel<<<BATCH * DIM * 4 / 256, 256, 0, stream>>>(U, prm_l, HB);
        apply_gemm_kernel<<<dim3(DIM / 128, BATCH * NCH), 256, 0, stream>>>(SA, HB, Zc, Zb);
        gemm_kernel<1><<<dim3(DIM / 128, BNROWS / 128), 256, 0, stream>>>(
            Zb, pwT + (size_t)l * DIM * DIM, k2_pb + (size_t)l * DIM, h, h, nullptr,
            BNROWS, DIM, DIM, DIM);
        rmsnorm_kernel<<<BNROWS, 256, 0, stream>>>(h, k2_n2w + (size_t)l * DIM, hnb);
        const float* nw_next = (l < NL - 1) ? (k2_n1w + (size_t)(l + 1) * DIM) : k1b_nw;
        mlp_core(w1T + (size_t)l * DIM * HID, k2_b1 + (size_t)l * HID,
                 w2T + (size_t)l * HID * DIM, k2_b2 + (size_t)l * DIM, nw_next);
    }

    mlp_core(w1bT, k1b_b1, w2bT, k1b_b2, k0_nw);    // -> hnb = rmsnorm(h, k0_nw)

    // head (4096 x 32000 x 1024)
    gemm256_kernel<0><<<dim3(VOC / 256, BNROWS / 256), 512, 131072, stream>>>(
        hnb, headT, head_b, out, nullptr, BNROWS, VOC, DIM, DIM);
}